// Round 10
// baseline (1942.177 us; speedup 1.0000x reference)
//
#include <hip/hip_runtime.h>
#include <hip/hip_bf16.h>

// ---------------------------------------------------------------------------
// GPT forward (B=4, T=1024, V=32000, C=768, L=6, H=12, HD=64).
// bf16 MFMA GEMMs (reg-staged, XOR-swizzled LDS — round-5 proven structure)
// + barrier-free flash attention (QBLK=32, 2-wave kv-split, V^T from global)
// + loss partials fused into the logits GEMM epilogue.
//
// R9:  2-D rectangle partition (8m x 125n per XCD): FETCH 104 MB, dur 312 —
//      A (1.57 MB/XCD) + B panels L2-RESIDENT.
// R10/R11: gload_lds single/double buffered: 389/362 us (worse; dead end).
// R12: split-K mlp2: regressed (contended atomics). Reverted.
// R13: K-loop unroll-by-2: regressed (VGPR 84->124 occupancy cliff). Reverted.
// R14: revert + single-pass LN (one barrier, was 16): 1524 us best.
//      Logits: VALUBusy 54.8 vs MfmaUtil 29.4 — the LDS round-trip IS the
//      remaining cost, and with L2-resident A/B it buys nothing (each staged
//      element consumed by only 2 waves).
// R15: logits GEMM fragment loads DIRECT FROM GLOBAL (L2-hit): no LDS, no
//      barriers, no staging. af[i]=A[m0+wr*64+(lane&15)+i*16][k+(lane>>4)*8]
//      (identical layout to the old LDS read — write XOR (row&7) == read XOR
//      (lane&7), LDS was a pass-through). Per instr: 16 rows x 64 contiguous
//      B = 16 aligned lines. L2 traffic ~24 TB/s < 34.5 ceiling. LDS 32KB->0
//      -> occupancy up; TLP + pipelining hide L2 latency.
//
// Memory plan:
//   d_out logits region (524 MB) = scratch until the final GEMM:
//     x(f32), qkvb(bf16: Q,K [t][d], V [d][t]), hb(bf16), bf16 weights.
//   d_ws tiers: xnb | lrow | pm,ps (loss partials) | Wbt   (~72 MB)
//               fallback: xnb | lrow | Wbt                 (~55.5 MB)
// ---------------------------------------------------------------------------

typedef __attribute__((ext_vector_type(8))) short          bh8;   // 8 bf16
typedef __attribute__((ext_vector_type(4))) unsigned short us4;
typedef __attribute__((ext_vector_type(4))) float          fl4;

__device__ inline unsigned short f2b(float f) {   // fp32 -> bf16 RNE
  unsigned u = __float_as_uint(f);
  return (unsigned short)((u + 0x7fffu + ((u >> 16) & 1u)) >> 16);
}

// ---------------------------------------------------------------------------
__global__ __launch_bounds__(256) void embed_kernel(
    const int* __restrict__ idx, const float* __restrict__ tok,
    const float* __restrict__ pos, float* __restrict__ x)
{
  int i = blockIdx.x * 256 + threadIdx.x;        // [0, 4096*768)
  int bt = i / 768, c = i - bt * 768;
  int t = bt & 1023;
  x[i] = tok[(size_t)idx[bt] * 768 + c] + pos[t * 768 + c];
}

// LayerNorm over rows of 768, fp32 in, bf16 out.  R14: single-pass
// (sum,sumsq) wave reduce — 6 shfl_xor + one 4-wide LDS combine; ONE barrier.
__global__ __launch_bounds__(256) void ln_bf16_kernel(
    const float* __restrict__ x, const float* __restrict__ s,
    const float* __restrict__ b, unsigned short* __restrict__ out)
{
  __shared__ float redS[4], redQ[4];
  int row = blockIdx.x, tid = threadIdx.x;
  const float* xr = x + (size_t)row * 768;
  float v0 = xr[tid], v1 = xr[tid + 256], v2 = xr[tid + 512];
  float sm = v0 + v1 + v2;
  float sq = v0 * v0 + v1 * v1 + v2 * v2;
#pragma unroll
  for (int m = 1; m < 64; m <<= 1) {
    sm += __shfl_xor(sm, m);
    sq += __shfl_xor(sq, m);
  }
  int wv = tid >> 6;
  if ((tid & 63) == 0) { redS[wv] = sm; redQ[wv] = sq; }
  __syncthreads();
  float ts = redS[0] + redS[1] + redS[2] + redS[3];
  float tq = redQ[0] + redQ[1] + redQ[2] + redQ[3];
  float mu = ts * (1.0f / 768.0f);
  float var = tq * (1.0f / 768.0f) - mu * mu;
  float inv = rsqrtf(var + 1e-5f);
  unsigned short* outr = out + (size_t)row * 768;
  outr[tid]       = f2b((v0 - mu) * inv * s[tid]       + b[tid]);
  outr[tid + 256] = f2b((v1 - mu) * inv * s[tid + 256] + b[tid + 256]);
  outr[tid + 512] = f2b((v2 - mu) * inv * s[tid + 512] + b[tid + 512]);
}

// ---------------------------------------------------------------------------
// Weight pre-transpose: fp32 [K][N] -> bf16 [N][K].  64x64 tiles.
__global__ __launch_bounds__(256) void tconv_kernel(
    const float* __restrict__ src, unsigned short* __restrict__ dst,
    int K, int N)
{
  __shared__ float tt[64][65];
  int n0 = blockIdx.x * 64, k0 = blockIdx.y * 64;
  const float* s = src + (size_t)blockIdx.z * K * N;
  unsigned short* d = dst + (size_t)blockIdx.z * K * N;
  int tx = threadIdx.x & 63, g = threadIdx.x >> 6;
#pragma unroll
  for (int i = 0; i < 16; ++i) {
    int k = g * 16 + i;
    tt[k][tx] = s[(size_t)(k0 + k) * N + n0 + tx];
  }
  __syncthreads();
#pragma unroll
  for (int i = 0; i < 16; ++i) {
    int n = g * 16 + i;
    d[(size_t)(n0 + n) * K + k0 + tx] = f2b(tt[tx][n]);
  }
}

// QKV weights: Wq[l][h][768][64] -> Wqkvt[l][which*768 + h*64 + d][768] bf16
__global__ __launch_bounds__(256) void tqkv_kernel(
    const float* __restrict__ src, unsigned short* __restrict__ dst, int which)
{
  __shared__ float tt[64][65];
  int k0 = blockIdx.x * 64;
  int z = blockIdx.y;                    // l*12 + h
  int l = z / 12, h = z - l * 12;
  const float* s = src + (size_t)z * 768 * 64;
  unsigned short* d = dst + (size_t)l * 2304 * 768 +
                      (size_t)(which * 768 + h * 64) * 768;
  int tx = threadIdx.x & 63, g = threadIdx.x >> 6;
#pragma unroll
  for (int i = 0; i < 16; ++i) {
    int k = g * 16 + i;
    tt[k][tx] = s[(size_t)(k0 + k) * 64 + tx];
  }
  __syncthreads();
#pragma unroll
  for (int i = 0; i < 16; ++i) {
    int n = g * 16 + i;
    d[(size_t)n * 768 + k0 + tx] = f2b(tt[tx][n]);
  }
}

// ---------------------------------------------------------------------------
// MFMA GEMM (round-5 structure): C = A @ Bt^T, 128x128 tile, BK=64, 4 waves,
// reg-staged XOR-swizzled LDS, register prefetch of tile t+1 before MFMA(t).
// MODE 0: qkv epilogue -> Q,K as [bh][t][64]; V TRANSPOSED as [bh][d][t].
// MODE 1: OutH = bf16(relu(acc + bias))   (mlp hidden, row-major)
// MODE 2: OutF += acc + bias              (residual accumulate, fp32)
template<int MODE>
__global__ __launch_bounds__(256) void gemm_bf16(
    const unsigned short* __restrict__ A, const unsigned short* __restrict__ Bt,
    const float* __restrict__ bias, float* __restrict__ OutF,
    unsigned short* __restrict__ OutH, int N, int K)
{
  __shared__ __align__(16) char As[128 * 64 * 2];
  __shared__ __align__(16) char Bs[128 * 64 * 2];
  const int tid = threadIdx.x;
  const int lane = tid & 63;
  const int wr = (tid >> 7) & 1, wc = (tid >> 6) & 1;
  const int m0 = blockIdx.y * 128, n0 = blockIdx.x * 128;
  const size_t Kb = (size_t)K * 2;

  fl4 acc[4][4] = {};
  const int o0 = tid * 16;
  const int rA = wr * 64 + (lane & 15);
  const int rB = wc * 64 + (lane & 15);
  const int kcol = (lane >> 4) << 4;
  const int sw = (lane & 7) << 4;

  auto ldAB = [&](int t, bh8* a, bh8* b) {
#pragma unroll
    for (int p = 0; p < 4; ++p) {
      int o = o0 + p * 4096;
      int row = o >> 7, col = o & 127;
      a[p] = *(const bh8*)((const char*)A + (size_t)(m0 + row) * Kb + (size_t)t * 128 + col);
      b[p] = *(const bh8*)((const char*)Bt + (size_t)(n0 + row) * Kb + (size_t)t * 128 + col);
    }
  };

  const int nK = K >> 6;
  bh8 ca[4], cb[4];
  ldAB(0, ca, cb);
  for (int t = 0; t < nK; ++t) {
    __syncthreads();                    // previous tile's LDS reads done
#pragma unroll
    for (int p = 0; p < 4; ++p) {
      int o = o0 + p * 4096;
      int row = o >> 7;
      int phys = o ^ ((row & 7) << 4);
      *(bh8*)(As + phys) = ca[p];
      *(bh8*)(Bs + phys) = cb[p];
    }
    __syncthreads();
    bh8 na[4], nb[4];
    const bool more = (t + 1 < nK);
    if (more) ldAB(t + 1, na, nb);      // issue early; consumed next iter
#pragma unroll
    for (int kh = 0; kh < 2; ++kh) {
      bh8 af[4], bf[4];
#pragma unroll
      for (int i = 0; i < 4; ++i) {
        af[i] = *(const bh8*)(As + (rA + i * 16) * 128 + ((kh * 64 + kcol) ^ sw));
        bf[i] = *(const bh8*)(Bs + (rB + i * 16) * 128 + ((kh * 64 + kcol) ^ sw));
      }
#pragma unroll
      for (int mi = 0; mi < 4; ++mi)
#pragma unroll
        for (int ni = 0; ni < 4; ++ni)
          acc[mi][ni] = __builtin_amdgcn_mfma_f32_16x16x32_bf16(
              af[mi], bf[ni], acc[mi][ni], 0, 0, 0);
    }
    if (more) {
#pragma unroll
      for (int p = 0; p < 4; ++p) { ca[p] = na[p]; cb[p] = nb[p]; }
    }
  }

  const int er = (lane >> 4) << 2;      // C/D: row=(lane>>4)*4+reg, col=lane&15
  const int ec = lane & 15;
#pragma unroll
  for (int mi = 0; mi < 4; ++mi)
#pragma unroll
    for (int ni = 0; ni < 4; ++ni)
#pragma unroll
      for (int r = 0; r < 4; ++r) {
        int m = m0 + wr * 64 + mi * 16 + er + r;
        int n = n0 + wc * 64 + ni * 16 + ec;
        float v = acc[mi][ni][r];
        if (MODE == 0) {
          int which = n / 768, rem = n - which * 768;
          int hh = rem >> 6, dd = rem & 63;
          int bb = m >> 10, tt = m & 1023;
          size_t base = (size_t)(which * 48 + bb * 12 + hh) << 16;
          if (which == 2)               // V stored transposed [d][t]
            OutH[base + (size_t)dd * 1024 + tt] = f2b(v);
          else
            OutH[base + (tt << 6) + dd] = f2b(v);
        } else if (MODE == 1) {
          v += bias[n]; v = fmaxf(v, 0.0f);
          OutH[(size_t)m * N + n] = f2b(v);
        } else {
          v += bias[n];
          OutF[(size_t)m * N + n] += v;
        }
      }
}

// ---------------------------------------------------------------------------
// Logits GEMM + fused loss partials (R15: LDS-FREE, barrier-free):
// Out[4096,32000] = xnb @ Wbt^T + bout.  Grid (8000,1).
// R9 map kept: tile grid 32m x 250n; each XCD (bid&7) owns an 8m x 125n
// rectangle, m-fastest inside -> A-quarter (1.57 MB) + B panels L2-resident.
// MFMA fragments load DIRECTLY from global (L2-hit):
//   af[i] = A[m0 + wr*64 + (lane&15) + i*16][k + (lane>>4)*8], k = ks*32
// (identical layout to the former LDS read path).  No LDS, no barriers.
// Out stores NON-TEMPORAL.  Partials indexed n_t*2+wc (500 groups).
__global__ __launch_bounds__(256) void gemm_logits_bt(
    const unsigned short* __restrict__ A, const unsigned short* __restrict__ Bt,
    const float* __restrict__ bias, float* __restrict__ Out,
    float* __restrict__ pm, float* __restrict__ ps)
{
  const int tid = threadIdx.x;
  const int lane = tid & 63;
  const int wr = (tid >> 7) & 1, wc = (tid >> 6) & 1;
  const int bid = blockIdx.x;
  const int xcd = bid & 7, lb = bid >> 3;           // lb in [0,1000)
  const int m_t = (xcd >> 1) * 8 + (lb & 7);        // 8 m-tiles per XCD
  const int n_t = (xcd & 1) * 125 + (lb >> 3);      // 125 n-tiles per XCD
  const int m0 = m_t * 128, n0 = n_t * 128;

  fl4 acc[4][4] = {};
  const int rrow = lane & 15;
  const int kofs = (lane >> 4) * 8;      // element offset within 32-elem step

  const unsigned short* Ar[4];
  const unsigned short* Br[4];
#pragma unroll
  for (int i = 0; i < 4; ++i) {
    Ar[i] = A  + (size_t)(m0 + wr * 64 + rrow + i * 16) * 768 + kofs;
    Br[i] = Bt + (size_t)(n0 + wc * 64 + rrow + i * 16) * 768 + kofs;
  }

#pragma unroll 4
  for (int ks = 0; ks < 24; ++ks) {      // K = 768 = 24 x 32
    bh8 af[4], bf[4];
#pragma unroll
    for (int i = 0; i < 4; ++i) {
      af[i] = *(const bh8*)(Ar[i] + ks * 32);
      bf[i] = *(const bh8*)(Br[i] + ks * 32);
    }
#pragma unroll
    for (int mi = 0; mi < 4; ++mi)
#pragma unroll
      for (int ni = 0; ni < 4; ++ni)
        acc[mi][ni] = __builtin_amdgcn_mfma_f32_16x16x32_bf16(
            af[mi], bf[ni], acc[mi][ni], 0, 0, 0);
  }

  const int er = (lane >> 4) << 2;
  const int ec = lane & 15;
#pragma unroll
  for (int mi = 0; mi < 4; ++mi)
#pragma unroll
    for (int r = 0; r < 4; ++r) {
      int m = m0 + wr * 64 + mi * 16 + er + r;
      float tv[4];
#pragma unroll
      for (int ni = 0; ni < 4; ++ni) {
        int n = n0 + wc * 64 + ni * 16 + ec;
        tv[ni] = acc[mi][ni][r] + bias[n];
        __builtin_nontemporal_store(tv[ni], &Out[(size_t)m * 32000 + n]);
      }
      if (pm) {
        float mx = fmaxf(fmaxf(tv[0], tv[1]), fmaxf(tv[2], tv[3]));
#pragma unroll
        for (int msk = 1; msk < 16; msk <<= 1)
          mx = fmaxf(mx, __shfl_xor(mx, msk));
        float ss = __expf(tv[0] - mx) + __expf(tv[1] - mx) +
                   __expf(tv[2] - mx) + __expf(tv[3] - mx);
#pragma unroll
        for (int msk = 1; msk < 16; msk <<= 1)
          ss += __shfl_xor(ss, msk);
        if (ec == 0) {
          pm[(size_t)m * 500 + n_t * 2 + wc] = mx;
          ps[(size_t)m * 500 + n_t * 2 + wc] = ss;
        }
      }
    }
}

// ---------------------------------------------------------------------------
// Fallback logits GEMM (in-kernel W fp32->bf16 staging).
__global__ __launch_bounds__(256) void gemm_logits(
    const unsigned short* __restrict__ A, const float* __restrict__ W,
    const float* __restrict__ bias, float* __restrict__ Out)
{
  __shared__ __align__(16) char As[256 * 64 * 2];   // 32 KB
  __shared__ __align__(16) char Bs[64 * 64 * 2];    // 8 KB
  const int tid = threadIdx.x, lane = tid & 63, wid = tid >> 6;
  const int m0 = blockIdx.y * 256, n0 = blockIdx.x * 64;
  const size_t Kb = 1536;

  fl4 acc[4][4] = {};
  const int o0 = tid * 16;
  const int rA = wid * 64 + (lane & 15);
  const int rB = (lane & 15);
  const int kcol = (lane >> 4) << 4;
  const int sw = (lane & 7) << 4;
  const int bn = tid & 63, bg = tid >> 6;

  for (int t = 0; t < 12; ++t) {
    bh8 ra[8];
#pragma unroll
    for (int p = 0; p < 8; ++p) {
      int o = o0 + p * 4096;
      int row = o >> 7, col = o & 127;
      ra[p] = *(const bh8*)((const char*)A + (size_t)(m0 + row) * Kb + (size_t)t * 128 + col);
    }
    unsigned short rb[16];
#pragma unroll
    for (int p = 0; p < 4; ++p) {
      int q = p * 4 + bg;               // k-quad 0..15
#pragma unroll
      for (int i = 0; i < 4; ++i)
        rb[p * 4 + i] = f2b(W[(size_t)(t * 64 + q * 4 + i) * 32000 + n0 + bn]);
    }
    __syncthreads();
#pragma unroll
    for (int p = 0; p < 8; ++p) {
      int o = o0 + p * 4096;
      int row = o >> 7;
      *(bh8*)(As + (o ^ ((row & 7) << 4))) = ra[p];
    }
#pragma unroll
    for (int p = 0; p < 4; ++p) {
      int q = p * 4 + bg;
      int o = bn * 128 + q * 8;
      us4 w4 = { rb[p * 4], rb[p * 4 + 1], rb[p * 4 + 2], rb[p * 4 + 3] };
      *(us4*)(Bs + (o ^ ((bn & 7) << 4))) = w4;
    }
    __syncthreads();
#pragma unroll
    for (int kh = 0; kh < 2; ++kh) {
      bh8 af[4], bf[4];
#pragma unroll
      for (int i = 0; i < 4; ++i) {
        af[i] = *(const bh8*)(As + (rA + i * 16) * 128 + ((kh * 64 + kcol) ^ sw));
        bf[i] = *(const bh8*)(Bs + (rB + i * 16) * 128 + ((kh * 64 + kcol) ^ sw));
      }
#pragma unroll
      for (int mi = 0; mi < 4; ++mi)
#pragma unroll
        for (int ni = 0; ni < 4; ++ni)
          acc[mi][ni] = __builtin_amdgcn_mfma_f32_16x16x32_bf16(
              af[mi], bf[ni], acc[mi][ni], 0, 0, 0);
    }
    __syncthreads();
  }

  const int er = (lane >> 4) << 2, ec = lane & 15;
#pragma unroll
  for (int mi = 0; mi < 4; ++mi)
#pragma unroll
    for (int ni = 0; ni < 4; ++ni)
#pragma unroll
      for (int r = 0; r < 4; ++r) {
        int m = m0 + wid * 64 + mi * 16 + er + r;
        int n = n0 + ni * 16 + ec;
        __builtin_nontemporal_store(acc[mi][ni][r] + bias[n],
                                    &Out[(size_t)m * 32000 + n]);
      }
}

// ---------------------------------------------------------------------------
// Flash attention, bf16 MFMA.  QBLK=32, 2 waves/block, kv-split by wave.
// Q,K layout [bh][t][64]; V layout [bh][d][t] (transposed by QKV epilogue) so
// PV B-fragments read directly from global — no V staging, and the kv loop is
// BARRIER-FREE (each wave's P-buffer is wave-private; lgkmcnt orders it).
__global__ __launch_bounds__(128) void attn_mfma_kernel(
    const unsigned short* __restrict__ qkvb, float* __restrict__ x)
{
  __shared__ __align__(16) unsigned short Pls[2][32 * 72];  // per-wave P
  __shared__ float MlLl[64];
  const int tid = threadIdx.x;
  const int lane = tid & 63, wv = tid >> 6;
  const int bh = blockIdx.y;
  const int b = bh / 12, h = bh - b * 12;
  const int qt = blockIdx.x, q0 = qt * 32;
  const int l15 = lane & 15, l4 = lane >> 4;
  const unsigned short* Qb = qkvb + ((size_t)bh << 16);
  const unsigned short* Kb = qkvb + ((size_t)(48 + bh) << 16);
  const unsigned short* Vb = qkvb + ((size_t)(96 + bh) << 16);  // [d][t]
  unsigned short* Pl = Pls[wv];

  bh8 qf[2][2];
#pragma unroll
  for (int mi = 0; mi < 2; ++mi)
#pragma unroll
    for (int kh = 0; kh < 2; ++kh)
      qf[mi][kh] = *(const bh8*)(Qb + (size_t)(q0 + mi * 16 + l15) * 64 + kh * 32 + l4 * 8);

  fl4 o_acc[2][4] = {};
  fl4 m_run[2], l_run[2];
#pragma unroll
  for (int mi = 0; mi < 2; ++mi) {
    m_run[mi] = fl4{-3e38f, -3e38f, -3e38f, -3e38f};
    l_run[mi] = fl4{0.f, 0.f, 0.f, 0.f};
  }

  const int nkv = (qt >> 1) + 1;        // # of 64-wide kv tiles needed
  for (int j = wv; j < nkv; j += 2) {   // barrier-free: waves independent
    const int kv0 = j * 64;
    fl4 s[2][4] = {};
#pragma unroll
    for (int kh = 0; kh < 2; ++kh) {
      bh8 kf[4];
#pragma unroll
      for (int ni = 0; ni < 4; ++ni)
        kf[ni] = *(const bh8*)(Kb + (size_t)(kv0 + ni * 16 + l15) * 64 + kh * 32 + l4 * 8);
#pragma unroll
      for (int mi = 0; mi < 2; ++mi)
#pragma unroll
        for (int ni = 0; ni < 4; ++ni)
          s[mi][ni] = __builtin_amdgcn_mfma_f32_16x16x32_bf16(
              qf[mi][kh], kf[ni], s[mi][ni], 0, 0, 0);
    }

    const bool needmask = (kv0 + 63 > q0);
#pragma unroll
    for (int mi = 0; mi < 2; ++mi) {
#pragma unroll
      for (int r = 0; r < 4; ++r) {
        float mx = -3e38f;
#pragma unroll
        for (int ni = 0; ni < 4; ++ni) {
          float sv = s[mi][ni][r] * 0.125f;
          if (needmask) {
            int qg = q0 + mi * 16 + l4 * 4 + r;
            int kg = kv0 + ni * 16 + l15;
            if (kg > qg) sv = -3e38f;
          }
          s[mi][ni][r] = sv;
          mx = fmaxf(mx, sv);
        }
#pragma unroll
        for (int msk = 1; msk < 16; msk <<= 1)
          mx = fmaxf(mx, __shfl_xor(mx, msk));
        float mo = m_run[mi][r];
        float mn = fmaxf(mo, mx);
        float scale = __expf(mo - mn);
        float rsum = 0.f;
#pragma unroll
        for (int ni = 0; ni < 4; ++ni) {
          float p = __expf(s[mi][ni][r] - mn);
          s[mi][ni][r] = p;
          rsum += p;
        }
#pragma unroll
        for (int msk = 1; msk < 16; msk <<= 1)
          rsum += __shfl_xor(rsum, msk);
        m_run[mi][r] = mn;
        l_run[mi][r] = l_run[mi][r] * scale + rsum;
#pragma unroll
        for (int ni = 0; ni < 4; ++ni)
          o_acc[mi][ni][r] *= scale;
      }
#pragma unroll
      for (int ni = 0; ni < 4; ++ni)
#pragma unroll
        for (int r = 0; r < 4; ++r)
          Pl[(mi * 16 + l4 * 4 + r) * 72 + ni * 16 + l15] = f2b(s[mi][ni][r]);
    }

    // O += P V  (P from wave-private LDS; V^T frags straight from global)
#pragma unroll
    for (int kh = 0; kh < 2; ++kh) {
      bh8 pf[2], vf[4];
#pragma unroll
      for (int mi = 0; mi < 2; ++mi)
        pf[mi] = *(const bh8*)(Pl + (mi * 16 + l15) * 72 + kh * 32 + l4 * 8);
#pragma unroll
      for (int ni = 0; ni < 4; ++ni)
        vf[ni] = *(const bh8*)(Vb + (size_t)(ni * 16 + l15) * 1024 + kv0 + kh * 32 + l4 * 8);
#pragma unroll
      for (int mi = 0; mi < 2; ++mi)
#pragma unroll
        for (int ni = 0; ni < 4; ++ni)
          o_acc[mi][ni] = __builtin_amdgcn_mfma_f32_16x16x32_bf16(
              pf[mi], vf[ni], o_acc[mi][ni], 0, 0, 0);
    }
  }

  // ---- merge the two partials (flash merge), wave 0 finalizes ----
  __syncthreads();
  float* Ol = (float*)&Pls[0][0];       // 32x68 f32 = 8704 B, fits both bufs
  if (wv == 1) {
#pragma unroll
    for (int mi = 0; mi < 2; ++mi)
#pragma unroll
      for (int r = 0; r < 4; ++r) {
        int row = mi * 16 + l4 * 4 + r;
        if (l15 == 0) { MlLl[row] = m_run[mi][r]; MlLl[32 + row] = l_run[mi][r]; }
#pragma unroll
        for (int ni = 0; ni < 4; ++ni)
          Ol[row * 68 + ni * 16 + l15] = o_acc[mi][ni][r];
      }
  }
  __syncthreads();
  if (wv == 0) {
#pragma unroll
    for (int mi = 0; mi < 2; ++mi)
#pragma unroll
      for (int r = 0; r < 4; ++r) {
        int row = mi * 16 + l4 * 4 + r;
        float m1 = MlLl[row], l1 = MlLl[32 + row];
        float m0v = m_run[mi][r];
        float mn = fmaxf(m0v, m1);
        float s0 = __expf(m0v - mn), s1 = __expf(m1 - mn);
        float inv = 1.0f / (l_run[mi][r] * s0 + l1 * s1);
        int q = q0 + row;
#pragma unroll
        for (int ni = 0; ni < 4; ++ni) {
          int d = ni * 16 + l15;
          float o = o_acc[mi][ni][r] * s0 + Ol[row * 68 + ni * 16 + l15] * s1;
          x[(size_t)(b * 1024 + q) * 768 + h * 64 + d] += o * inv;
        }
      }
  }
}

// ---------------------------------------------------------------------------
// Merge per-block loss partials: lrow[row] = (logsumexp - logit[target])/4096
__global__ __launch_bounds__(256) void lossmerge_kernel(
    const float* __restrict__ pm, const float* __restrict__ ps,
    const float* __restrict__ logits, const int* __restrict__ targets,
    float* __restrict__ lrow)
{
  __shared__ float red[256];
  int row = blockIdx.x, tid = threadIdx.x;
  const float* pmr = pm + (size_t)row * 500;
  const float* psr = ps + (size_t)row * 500;
  float m = -3e38f;
  for (int i = tid; i < 500; i += 256) m = fmaxf(m, pmr[i]);
  red[tid] = m; __syncthreads();
  for (int o = 128; o > 0; o >>= 1) { if (tid < o) red[tid] = fmaxf(red[tid], red[tid + o]); __syncthreads(); }
  m = red[0]; __syncthreads();
  float s = 0.f;
  for (int i = tid; i < 500; i += 256) s += psr[i] * __expf(pmr[i] - m);
  red[tid] = s; __syncthreads();
  for (int o = 128; o > 0; o >>= 1) { if (tid < o) red[tid] += red[tid + o]; __syncthreads(); }
  if (tid == 0) {
    float lse = m + logf(red[0]);
    lrow[row] = (lse - logits[(size_t)row * 32000 + targets[row]]) * (1.0f / 4096.0f);
  }
}

// Standalone per-row cross-entropy (fallback when ws too small for partials).
__global__ __launch_bounds__(256) void lossrow_kernel(
    const float* __restrict__ logits, const int* __restrict__ targets,
    float* __restrict__ lrow)
{
  __shared__ float red[256];
  int row = blockIdx.x, tid = threadIdx.x;
  const float* lr = logits + (size_t)row * 32000;
  const float4* lr4 = (const float4*)lr;
  float lmax = -1e30f;
  for (int i = tid; i < 8000; i += 256) {
    float4 v = lr4[i];
    lmax = fmaxf(fmaxf(lmax, fmaxf(v.x, v.y)), fmaxf(v.z, v.w));
  }
  red[tid] = lmax; __syncthreads();
  for (int o = 128; o > 0; o >>= 1) { if (tid < o) red[tid] = fmaxf(red[tid], red[tid + o]); __syncthreads(); }
  float m = red[0]; __syncthreads();
  float ls = 0.f;
  for (int i = tid; i < 8000; i += 256) {
    float4 v = lr4[i];
    ls += expf(v.x - m) + expf(v.y - m) + expf(v.z - m) + expf(v.w - m);
  }
  red[tid] = ls; __syncthreads();
  for (int o = 128; o > 0; o >>= 1) { if (tid < o) red[tid] += red[tid + o]; __syncthreads(); }
  if (tid == 0) {
    float lse = m + logf(red[0]);
    lrow[row] = (lse - lr[targets[row]]) * (1.0f / 4096.0f);
  }
}

__global__ __launch_bounds__(256) void lossred_kernel(
    const float* __restrict__ lrow, float* __restrict__ out)
{
  __shared__ float red[256];
  int tid = threadIdx.x;
  float s = 0.f;
  for (int i = tid; i < 4096; i += 256) s += lrow[i];
  red[tid] = s; __syncthreads();
  for (int o = 128; o > 0; o >>= 1) { if (tid < o) red[tid] += red[tid + o]; __syncthreads(); }
  if (tid == 0) out[0] = red[0];
}

// ---------------------------------------------------------------------------
extern "C" void kernel_launch(void* const* d_in, const int* in_sizes, int n_in,
                              void* d_out, int out_size, void* d_ws, size_t ws_size,
                              hipStream_t stream)
{
  (void)in_sizes; (void)n_in; (void)out_size;
  const int Bq = 4, T = 1024, V = 32000, C = 768, L = 6;
  const int M = Bq * T;   // 4096

  const int*   idx     = (const int*)d_in[0];
  const int*   targets = (const int*)d_in[1];
  const float* tok     = (const float*)d_in[2];
  const float* pos     = (const float*)d_in[3];
  const float* Wq      = (const float*)d_in[4];
  const float* Wk      = (const float*)d_in[5];
  const float* Wv      = (const float*)d_in[6];
  const float* ln1s    = (const float*)d_in[7];
  const float* ln1b    = (const float*)d_in[8];
  const float* ln2s    = (const float*)d_in[9];
  const float* ln2b    = (const float*)d_in[10];
  const float* W1      = (const float*)d_in[11];
  const float* b1      = (const float*)d_in[12];
  const float* W2      = (const float*)d_in[13];
  const float* b2      = (const float*)d_in[14];
  const float* lnfs    = (const float*)d_in[15];
  const float* lnfb    = (const float*)d_in[16];
  const float* Wout    = (const float*)d_in[17];
  const float* bout    = (const float*)d_in[18];
  float* out = (float*)d_out;

  // ---- scratch inside d_out's logits region (dead until logits GEMM) ----
  char* ob = (char*)d_out;
  size_t oo = 0;
  auto oa = [&](size_t bytes) {
    void* p = ob + oo; oo += (bytes + 255) & ~(size_t)255; return p;
  };
  float*          x     = (float*)oa((size_t)M * C * 4);              // 12.6 MB
  unsigned short* qkvb  = (unsigned short*)oa((size_t)3 * 48 * 65536 * 2); // 18.9 MB
  unsigned short* hb    = (unsigned short*)oa((size_t)M * 3072 * 2);  // 25.2 MB
  unsigned short* Wqkvt = (unsigned short*)oa((size_t)L * 2304 * C * 2);
  unsigned short* W1t   = (unsigned short*)oa((size_t)L * C * 3072 * 2);
  unsigned short* W2t   = (unsigned short*)oa((size_t)L * C * 3072 * 2);
  // total ~135 MB << 524 MB logits region

  // ---- d_ws tiers ----
  char* wp = (char*)d_ws;
  unsigned short* xnb  = (unsigned short*)wp;                      // 6.29 MB
  float*          lrow = (float*)(wp + (size_t)M * C * 2);         // 16 KB
  float*          pm   = (float*)(wp + (size_t)M * C * 2 + 16384);
  float*          ps   = pm + (size_t)M * 500;                     // 2x 8.19 MB
  const size_t off_wbt_full  = (size_t)M * C * 2 + 16384 + (size_t)M * 500 * 8;
  const size_t off_wbt_small = (size_t)M * C * 2 + 16384;
  const size_t wbt_bytes = (size_t)V * C * 2;                      // 49.15 MB
  const bool full_ws = ws_size >= off_wbt_full + wbt_bytes;        // ~72 MB
  const bool wbt_ok  = full_ws || ws_size >= off_wbt_small + wbt_bytes;
  unsigned short* Wbt = (unsigned short*)(wp + (full_ws ? off_wbt_full
                                                        : off_wbt_small));

  // ---- pre-pass: embed + weight transpose/convert ----
  embed_kernel<<<(M * C) / 256, 256, 0, stream>>>(idx, tok, pos, x);
  tqkv_kernel<<<dim3(12, 72), 256, 0, stream>>>(Wq, Wqkvt, 0);
  tqkv_kernel<<<dim3(12, 72), 256, 0, stream>>>(Wk, Wqkvt, 1);
  tqkv_kernel<<<dim3(12, 72), 256, 0, stream>>>(Wv, Wqkvt, 2);
  tconv_kernel<<<dim3(48, 12, 6), 256, 0, stream>>>(W1, W1t, C, 3072);
  tconv_kernel<<<dim3(12, 48, 6), 256, 0, stream>>>(W2, W2t, 3072, C);
  if (wbt_ok)
    tconv_kernel<<<dim3(500, 12, 1), 256, 0, stream>>>(Wout, Wbt, C, V);

  for (int l = 0; l < L; ++l) {
    ln_bf16_kernel<<<M, 256, 0, stream>>>(x, ln1s + l * C, ln1b + l * C, xnb);
    gemm_bf16<0><<<dim3(18, 32), 256, 0, stream>>>(
        xnb, Wqkvt + (size_t)l * 2304 * C, nullptr, nullptr, qkvb, 2304, C);
    attn_mfma_kernel<<<dim3(32, 48), 128, 0, stream>>>(qkvb, x);
    ln_bf16_kernel<<<M, 256, 0, stream>>>(x, ln2s + l * C, ln2b + l * C, xnb);
    gemm_bf16<1><<<dim3(24, 32), 256, 0, stream>>>(
        xnb, W1t + (size_t)l * C * 3072, b1 + (size_t)l * 3072, nullptr, hb, 3072, C);
    gemm_bf16<2><<<dim3(6, 32), 256, 0, stream>>>(
        hb, W2t + (size_t)l * C * 3072, b2 + (size_t)l * C, x, nullptr, C, 3072);
  }

  ln_bf16_kernel<<<M, 256, 0, stream>>>(x, lnfs, lnfb, xnb);
  if (wbt_ok)
    gemm_logits_bt<<<dim3(8000, 1), 256, 0, stream>>>(
        xnb, Wbt, bout, out, full_ws ? pm : nullptr, full_ws ? ps : nullptr);
  else
    gemm_logits<<<dim3(500, 16), 256, 0, stream>>>(xnb, Wout, bout, out);

  if (full_ws && wbt_ok)
    lossmerge_kernel<<<M, 256, 0, stream>>>(pm, ps, out, targets, lrow);
  else
    lossrow_kernel<<<M, 256, 0, stream>>>(out, targets, lrow);
  lossred_kernel<<<1, 256, 0, stream>>>(lrow, out + (size_t)M * V);
}

// Round 11
// 1520.497 us; speedup vs baseline: 1.2773x; 1.2773x over previous
//
#include <hip/hip_runtime.h>
#include <hip/hip_bf16.h>

// ---------------------------------------------------------------------------
// GPT forward (B=4, T=1024, V=32000, C=768, L=6, H=12, HD=64).
// bf16 MFMA GEMMs (reg-staged, XOR-swizzled LDS — round-5 proven structure)
// + barrier-free flash attention (QBLK=32, 2-wave kv-split, V^T from global)
// + loss partials fused into the logits GEMM epilogue.
//
// R9:  2-D rectangle partition (8m x 125n per XCD): FETCH 104 MB, dur 312 —
//      A (1.57 MB/XCD) + B panels L2-RESIDENT.
// R10/R11: gload_lds single/double buffered: 389/362 us (dead end).
// R12: split-K mlp2: regressed (contended atomics). Reverted.
// R13: K-loop unroll-by-2: regressed (VGPR 84->124 occupancy cliff). Reverted.
// R14: revert + single-pass LN (one barrier, was 16): 1524 us BEST.
// R15: LDS-free logits (direct L2 fragment loads): 752 us — latency-bound
//      (MfmaUtil 10.9, VALUBusy 12.7: 8 loads x 16 lines in flight vs
//      ~200-450cy L2 latency; the LDS tile was the decoupling buffer, not a
//      pass-through). REVERTED.
// R16: exact R14 restore. Ledger: schedule-structure changes 0/4, placement/
//      epilogue changes 3/3 — remaining structural ports judged negative-EV.
//
// Memory plan:
//   d_out logits region (524 MB) = scratch until the final GEMM:
//     x(f32), qkvb(bf16: Q,K [t][d], V [d][t]), hb(bf16), bf16 weights.
//   d_ws tiers: xnb | lrow | pm,ps (loss partials) | Wbt   (~72 MB)
//               fallback: xnb | lrow | Wbt                 (~55.5 MB)
// ---------------------------------------------------------------------------

typedef __attribute__((ext_vector_type(8))) short          bh8;   // 8 bf16
typedef __attribute__((ext_vector_type(4))) unsigned short us4;
typedef __attribute__((ext_vector_type(4))) float          fl4;

__device__ inline unsigned short f2b(float f) {   // fp32 -> bf16 RNE
  unsigned u = __float_as_uint(f);
  return (unsigned short)((u + 0x7fffu + ((u >> 16) & 1u)) >> 16);
}

// ---------------------------------------------------------------------------
__global__ __launch_bounds__(256) void embed_kernel(
    const int* __restrict__ idx, const float* __restrict__ tok,
    const float* __restrict__ pos, float* __restrict__ x)
{
  int i = blockIdx.x * 256 + threadIdx.x;        // [0, 4096*768)
  int bt = i / 768, c = i - bt * 768;
  int t = bt & 1023;
  x[i] = tok[(size_t)idx[bt] * 768 + c] + pos[t * 768 + c];
}

// LayerNorm over rows of 768, fp32 in, bf16 out.  R14: single-pass
// (sum,sumsq) wave reduce — 6 shfl_xor + one 4-wide LDS combine; ONE barrier.
__global__ __launch_bounds__(256) void ln_bf16_kernel(
    const float* __restrict__ x, const float* __restrict__ s,
    const float* __restrict__ b, unsigned short* __restrict__ out)
{
  __shared__ float redS[4], redQ[4];
  int row = blockIdx.x, tid = threadIdx.x;
  const float* xr = x + (size_t)row * 768;
  float v0 = xr[tid], v1 = xr[tid + 256], v2 = xr[tid + 512];
  float sm = v0 + v1 + v2;
  float sq = v0 * v0 + v1 * v1 + v2 * v2;
#pragma unroll
  for (int m = 1; m < 64; m <<= 1) {
    sm += __shfl_xor(sm, m);
    sq += __shfl_xor(sq, m);
  }
  int wv = tid >> 6;
  if ((tid & 63) == 0) { redS[wv] = sm; redQ[wv] = sq; }
  __syncthreads();
  float ts = redS[0] + redS[1] + redS[2] + redS[3];
  float tq = redQ[0] + redQ[1] + redQ[2] + redQ[3];
  float mu = ts * (1.0f / 768.0f);
  float var = tq * (1.0f / 768.0f) - mu * mu;
  float inv = rsqrtf(var + 1e-5f);
  unsigned short* outr = out + (size_t)row * 768;
  outr[tid]       = f2b((v0 - mu) * inv * s[tid]       + b[tid]);
  outr[tid + 256] = f2b((v1 - mu) * inv * s[tid + 256] + b[tid + 256]);
  outr[tid + 512] = f2b((v2 - mu) * inv * s[tid + 512] + b[tid + 512]);
}

// ---------------------------------------------------------------------------
// Weight pre-transpose: fp32 [K][N] -> bf16 [N][K].  64x64 tiles.
__global__ __launch_bounds__(256) void tconv_kernel(
    const float* __restrict__ src, unsigned short* __restrict__ dst,
    int K, int N)
{
  __shared__ float tt[64][65];
  int n0 = blockIdx.x * 64, k0 = blockIdx.y * 64;
  const float* s = src + (size_t)blockIdx.z * K * N;
  unsigned short* d = dst + (size_t)blockIdx.z * K * N;
  int tx = threadIdx.x & 63, g = threadIdx.x >> 6;
#pragma unroll
  for (int i = 0; i < 16; ++i) {
    int k = g * 16 + i;
    tt[k][tx] = s[(size_t)(k0 + k) * N + n0 + tx];
  }
  __syncthreads();
#pragma unroll
  for (int i = 0; i < 16; ++i) {
    int n = g * 16 + i;
    d[(size_t)(n0 + n) * K + k0 + tx] = f2b(tt[tx][n]);
  }
}

// QKV weights: Wq[l][h][768][64] -> Wqkvt[l][which*768 + h*64 + d][768] bf16
__global__ __launch_bounds__(256) void tqkv_kernel(
    const float* __restrict__ src, unsigned short* __restrict__ dst, int which)
{
  __shared__ float tt[64][65];
  int k0 = blockIdx.x * 64;
  int z = blockIdx.y;                    // l*12 + h
  int l = z / 12, h = z - l * 12;
  const float* s = src + (size_t)z * 768 * 64;
  unsigned short* d = dst + (size_t)l * 2304 * 768 +
                      (size_t)(which * 768 + h * 64) * 768;
  int tx = threadIdx.x & 63, g = threadIdx.x >> 6;
#pragma unroll
  for (int i = 0; i < 16; ++i) {
    int k = g * 16 + i;
    tt[k][tx] = s[(size_t)(k0 + k) * 64 + tx];
  }
  __syncthreads();
#pragma unroll
  for (int i = 0; i < 16; ++i) {
    int n = g * 16 + i;
    d[(size_t)n * 768 + k0 + tx] = f2b(tt[tx][n]);
  }
}

// ---------------------------------------------------------------------------
// MFMA GEMM (round-5 structure): C = A @ Bt^T, 128x128 tile, BK=64, 4 waves,
// reg-staged XOR-swizzled LDS, register prefetch of tile t+1 before MFMA(t).
// MODE 0: qkv epilogue -> Q,K as [bh][t][64]; V TRANSPOSED as [bh][d][t].
// MODE 1: OutH = bf16(relu(acc + bias))   (mlp hidden, row-major)
// MODE 2: OutF += acc + bias              (residual accumulate, fp32)
template<int MODE>
__global__ __launch_bounds__(256) void gemm_bf16(
    const unsigned short* __restrict__ A, const unsigned short* __restrict__ Bt,
    const float* __restrict__ bias, float* __restrict__ OutF,
    unsigned short* __restrict__ OutH, int N, int K)
{
  __shared__ __align__(16) char As[128 * 64 * 2];
  __shared__ __align__(16) char Bs[128 * 64 * 2];
  const int tid = threadIdx.x;
  const int lane = tid & 63;
  const int wr = (tid >> 7) & 1, wc = (tid >> 6) & 1;
  const int m0 = blockIdx.y * 128, n0 = blockIdx.x * 128;
  const size_t Kb = (size_t)K * 2;

  fl4 acc[4][4] = {};
  const int o0 = tid * 16;
  const int rA = wr * 64 + (lane & 15);
  const int rB = wc * 64 + (lane & 15);
  const int kcol = (lane >> 4) << 4;
  const int sw = (lane & 7) << 4;

  auto ldAB = [&](int t, bh8* a, bh8* b) {
#pragma unroll
    for (int p = 0; p < 4; ++p) {
      int o = o0 + p * 4096;
      int row = o >> 7, col = o & 127;
      a[p] = *(const bh8*)((const char*)A + (size_t)(m0 + row) * Kb + (size_t)t * 128 + col);
      b[p] = *(const bh8*)((const char*)Bt + (size_t)(n0 + row) * Kb + (size_t)t * 128 + col);
    }
  };

  const int nK = K >> 6;
  bh8 ca[4], cb[4];
  ldAB(0, ca, cb);
  for (int t = 0; t < nK; ++t) {
    __syncthreads();                    // previous tile's LDS reads done
#pragma unroll
    for (int p = 0; p < 4; ++p) {
      int o = o0 + p * 4096;
      int row = o >> 7;
      int phys = o ^ ((row & 7) << 4);
      *(bh8*)(As + phys) = ca[p];
      *(bh8*)(Bs + phys) = cb[p];
    }
    __syncthreads();
    bh8 na[4], nb[4];
    const bool more = (t + 1 < nK);
    if (more) ldAB(t + 1, na, nb);      // issue early; consumed next iter
#pragma unroll
    for (int kh = 0; kh < 2; ++kh) {
      bh8 af[4], bf[4];
#pragma unroll
      for (int i = 0; i < 4; ++i) {
        af[i] = *(const bh8*)(As + (rA + i * 16) * 128 + ((kh * 64 + kcol) ^ sw));
        bf[i] = *(const bh8*)(Bs + (rB + i * 16) * 128 + ((kh * 64 + kcol) ^ sw));
      }
#pragma unroll
      for (int mi = 0; mi < 4; ++mi)
#pragma unroll
        for (int ni = 0; ni < 4; ++ni)
          acc[mi][ni] = __builtin_amdgcn_mfma_f32_16x16x32_bf16(
              af[mi], bf[ni], acc[mi][ni], 0, 0, 0);
    }
    if (more) {
#pragma unroll
      for (int p = 0; p < 4; ++p) { ca[p] = na[p]; cb[p] = nb[p]; }
    }
  }

  const int er = (lane >> 4) << 2;      // C/D: row=(lane>>4)*4+reg, col=lane&15
  const int ec = lane & 15;
#pragma unroll
  for (int mi = 0; mi < 4; ++mi)
#pragma unroll
    for (int ni = 0; ni < 4; ++ni)
#pragma unroll
      for (int r = 0; r < 4; ++r) {
        int m = m0 + wr * 64 + mi * 16 + er + r;
        int n = n0 + wc * 64 + ni * 16 + ec;
        float v = acc[mi][ni][r];
        if (MODE == 0) {
          int which = n / 768, rem = n - which * 768;
          int hh = rem >> 6, dd = rem & 63;
          int bb = m >> 10, tt = m & 1023;
          size_t base = (size_t)(which * 48 + bb * 12 + hh) << 16;
          if (which == 2)               // V stored transposed [d][t]
            OutH[base + (size_t)dd * 1024 + tt] = f2b(v);
          else
            OutH[base + (tt << 6) + dd] = f2b(v);
        } else if (MODE == 1) {
          v += bias[n]; v = fmaxf(v, 0.0f);
          OutH[(size_t)m * N + n] = f2b(v);
        } else {
          v += bias[n];
          OutF[(size_t)m * N + n] += v;
        }
      }
}

// ---------------------------------------------------------------------------
// Logits GEMM + fused loss partials (R9/R12, harness-measured 301-312 us):
// Out[4096,32000] = xnb @ Wbt^T + bout.  Grid (8000,1).
// Tile grid 32m x 250n; each XCD (bid&7) owns an 8m x 125n rectangle,
// m-fastest inside -> per-XCD L2 working set (A-quarter 1.57 MB + ~10 B
// panels) < 4 MB L2; reads don't depend on L3 (which the 578 MB write
// stream thrashes).  Reg-staged XOR-swizzled LDS with t+1 reg prefetch.
// Out stores NON-TEMPORAL.  Partials indexed n_t*2+wc (500 groups).
__global__ __launch_bounds__(256) void gemm_logits_bt(
    const unsigned short* __restrict__ A, const unsigned short* __restrict__ Bt,
    const float* __restrict__ bias, float* __restrict__ Out,
    float* __restrict__ pm, float* __restrict__ ps)
{
  __shared__ __align__(16) char As[128 * 64 * 2];
  __shared__ __align__(16) char Bs[128 * 64 * 2];
  const int tid = threadIdx.x;
  const int lane = tid & 63;
  const int wr = (tid >> 7) & 1, wc = (tid >> 6) & 1;
  const int bid = blockIdx.x;
  const int xcd = bid & 7, lb = bid >> 3;           // lb in [0,1000)
  const int m_t = (xcd >> 1) * 8 + (lb & 7);        // 8 m-tiles per XCD
  const int n_t = (xcd & 1) * 125 + (lb >> 3);      // 125 n-tiles per XCD
  const int m0 = m_t * 128, n0 = n_t * 128;
  const size_t Kb = 1536;               // K=768 bf16

  fl4 acc[4][4] = {};
  const int o0 = tid * 16;
  const int rA = wr * 64 + (lane & 15);
  const int rB = wc * 64 + (lane & 15);
  const int kcol = (lane >> 4) << 4;
  const int sw = (lane & 7) << 4;

  auto ldAB = [&](int t, bh8* a, bh8* b) {
#pragma unroll
    for (int p = 0; p < 4; ++p) {
      int o = o0 + p * 4096;
      int row = o >> 7, col = o & 127;
      a[p] = *(const bh8*)((const char*)A + (size_t)(m0 + row) * Kb + (size_t)t * 128 + col);
      b[p] = *(const bh8*)((const char*)Bt + (size_t)(n0 + row) * Kb + (size_t)t * 128 + col);
    }
  };

  const int nK = 12;                    // 768 / 64
  bh8 ca[4], cb[4];
  ldAB(0, ca, cb);
  for (int t = 0; t < nK; ++t) {
    __syncthreads();                    // previous tile's LDS reads done
#pragma unroll
    for (int p = 0; p < 4; ++p) {
      int o = o0 + p * 4096;
      int row = o >> 7;
      int phys = o ^ ((row & 7) << 4);
      *(bh8*)(As + phys) = ca[p];
      *(bh8*)(Bs + phys) = cb[p];
    }
    __syncthreads();
    bh8 na[4], nb[4];
    const bool more = (t + 1 < nK);
    if (more) ldAB(t + 1, na, nb);      // issue early; consumed next iter
#pragma unroll
    for (int kh = 0; kh < 2; ++kh) {
      bh8 af[4], bf[4];
#pragma unroll
      for (int i = 0; i < 4; ++i) {
        af[i] = *(const bh8*)(As + (rA + i * 16) * 128 + ((kh * 64 + kcol) ^ sw));
        bf[i] = *(const bh8*)(Bs + (rB + i * 16) * 128 + ((kh * 64 + kcol) ^ sw));
      }
#pragma unroll
      for (int mi = 0; mi < 4; ++mi)
#pragma unroll
        for (int ni = 0; ni < 4; ++ni)
          acc[mi][ni] = __builtin_amdgcn_mfma_f32_16x16x32_bf16(
              af[mi], bf[ni], acc[mi][ni], 0, 0, 0);
    }
    if (more) {
#pragma unroll
      for (int p = 0; p < 4; ++p) { ca[p] = na[p]; cb[p] = nb[p]; }
    }
  }

  const int er = (lane >> 4) << 2;
  const int ec = lane & 15;
#pragma unroll
  for (int mi = 0; mi < 4; ++mi)
#pragma unroll
    for (int r = 0; r < 4; ++r) {
      int m = m0 + wr * 64 + mi * 16 + er + r;
      float tv[4];
#pragma unroll
      for (int ni = 0; ni < 4; ++ni) {
        int n = n0 + wc * 64 + ni * 16 + ec;
        tv[ni] = acc[mi][ni][r] + bias[n];
        __builtin_nontemporal_store(tv[ni], &Out[(size_t)m * 32000 + n]);
      }
      if (pm) {
        float mx = fmaxf(fmaxf(tv[0], tv[1]), fmaxf(tv[2], tv[3]));
#pragma unroll
        for (int msk = 1; msk < 16; msk <<= 1)
          mx = fmaxf(mx, __shfl_xor(mx, msk));
        float ss = __expf(tv[0] - mx) + __expf(tv[1] - mx) +
                   __expf(tv[2] - mx) + __expf(tv[3] - mx);
#pragma unroll
        for (int msk = 1; msk < 16; msk <<= 1)
          ss += __shfl_xor(ss, msk);
        if (ec == 0) {
          pm[(size_t)m * 500 + n_t * 2 + wc] = mx;
          ps[(size_t)m * 500 + n_t * 2 + wc] = ss;
        }
      }
    }
}

// ---------------------------------------------------------------------------
// Fallback logits GEMM (in-kernel W fp32->bf16 staging).
__global__ __launch_bounds__(256) void gemm_logits(
    const unsigned short* __restrict__ A, const float* __restrict__ W,
    const float* __restrict__ bias, float* __restrict__ Out)
{
  __shared__ __align__(16) char As[256 * 64 * 2];   // 32 KB
  __shared__ __align__(16) char Bs[64 * 64 * 2];    // 8 KB
  const int tid = threadIdx.x, lane = tid & 63, wid = tid >> 6;
  const int m0 = blockIdx.y * 256, n0 = blockIdx.x * 64;
  const size_t Kb = 1536;

  fl4 acc[4][4] = {};
  const int o0 = tid * 16;
  const int rA = wid * 64 + (lane & 15);
  const int rB = (lane & 15);
  const int kcol = (lane >> 4) << 4;
  const int sw = (lane & 7) << 4;
  const int bn = tid & 63, bg = tid >> 6;

  for (int t = 0; t < 12; ++t) {
    bh8 ra[8];
#pragma unroll
    for (int p = 0; p < 8; ++p) {
      int o = o0 + p * 4096;
      int row = o >> 7, col = o & 127;
      ra[p] = *(const bh8*)((const char*)A + (size_t)(m0 + row) * Kb + (size_t)t * 128 + col);
    }
    unsigned short rb[16];
#pragma unroll
    for (int p = 0; p < 4; ++p) {
      int q = p * 4 + bg;               // k-quad 0..15
#pragma unroll
      for (int i = 0; i < 4; ++i)
        rb[p * 4 + i] = f2b(W[(size_t)(t * 64 + q * 4 + i) * 32000 + n0 + bn]);
    }
    __syncthreads();
#pragma unroll
    for (int p = 0; p < 8; ++p) {
      int o = o0 + p * 4096;
      int row = o >> 7;
      *(bh8*)(As + (o ^ ((row & 7) << 4))) = ra[p];
    }
#pragma unroll
    for (int p = 0; p < 4; ++p) {
      int q = p * 4 + bg;
      int o = bn * 128 + q * 8;
      us4 w4 = { rb[p * 4], rb[p * 4 + 1], rb[p * 4 + 2], rb[p * 4 + 3] };
      *(us4*)(Bs + (o ^ ((bn & 7) << 4))) = w4;
    }
    __syncthreads();
#pragma unroll
    for (int kh = 0; kh < 2; ++kh) {
      bh8 af[4], bf[4];
#pragma unroll
      for (int i = 0; i < 4; ++i) {
        af[i] = *(const bh8*)(As + (rA + i * 16) * 128 + ((kh * 64 + kcol) ^ sw));
        bf[i] = *(const bh8*)(Bs + (rB + i * 16) * 128 + ((kh * 64 + kcol) ^ sw));
      }
#pragma unroll
      for (int mi = 0; mi < 4; ++mi)
#pragma unroll
        for (int ni = 0; ni < 4; ++ni)
          acc[mi][ni] = __builtin_amdgcn_mfma_f32_16x16x32_bf16(
              af[mi], bf[ni], acc[mi][ni], 0, 0, 0);
    }
    __syncthreads();
  }

  const int er = (lane >> 4) << 2, ec = lane & 15;
#pragma unroll
  for (int mi = 0; mi < 4; ++mi)
#pragma unroll
    for (int ni = 0; ni < 4; ++ni)
#pragma unroll
      for (int r = 0; r < 4; ++r) {
        int m = m0 + wid * 64 + mi * 16 + er + r;
        int n = n0 + ni * 16 + ec;
        __builtin_nontemporal_store(acc[mi][ni][r] + bias[n],
                                    &Out[(size_t)m * 32000 + n]);
      }
}

// ---------------------------------------------------------------------------
// Flash attention, bf16 MFMA.  QBLK=32, 2 waves/block, kv-split by wave.
// Q,K layout [bh][t][64]; V layout [bh][d][t] (transposed by QKV epilogue) so
// PV B-fragments read directly from global — no V staging, and the kv loop is
// BARRIER-FREE (each wave's P-buffer is wave-private; lgkmcnt orders it).
__global__ __launch_bounds__(128) void attn_mfma_kernel(
    const unsigned short* __restrict__ qkvb, float* __restrict__ x)
{
  __shared__ __align__(16) unsigned short Pls[2][32 * 72];  // per-wave P
  __shared__ float MlLl[64];
  const int tid = threadIdx.x;
  const int lane = tid & 63, wv = tid >> 6;
  const int bh = blockIdx.y;
  const int b = bh / 12, h = bh - b * 12;
  const int qt = blockIdx.x, q0 = qt * 32;
  const int l15 = lane & 15, l4 = lane >> 4;
  const unsigned short* Qb = qkvb + ((size_t)bh << 16);
  const unsigned short* Kb = qkvb + ((size_t)(48 + bh) << 16);
  const unsigned short* Vb = qkvb + ((size_t)(96 + bh) << 16);  // [d][t]
  unsigned short* Pl = Pls[wv];

  bh8 qf[2][2];
#pragma unroll
  for (int mi = 0; mi < 2; ++mi)
#pragma unroll
    for (int kh = 0; kh < 2; ++kh)
      qf[mi][kh] = *(const bh8*)(Qb + (size_t)(q0 + mi * 16 + l15) * 64 + kh * 32 + l4 * 8);

  fl4 o_acc[2][4] = {};
  fl4 m_run[2], l_run[2];
#pragma unroll
  for (int mi = 0; mi < 2; ++mi) {
    m_run[mi] = fl4{-3e38f, -3e38f, -3e38f, -3e38f};
    l_run[mi] = fl4{0.f, 0.f, 0.f, 0.f};
  }

  const int nkv = (qt >> 1) + 1;        // # of 64-wide kv tiles needed
  for (int j = wv; j < nkv; j += 2) {   // barrier-free: waves independent
    const int kv0 = j * 64;
    fl4 s[2][4] = {};
#pragma unroll
    for (int kh = 0; kh < 2; ++kh) {
      bh8 kf[4];
#pragma unroll
      for (int ni = 0; ni < 4; ++ni)
        kf[ni] = *(const bh8*)(Kb + (size_t)(kv0 + ni * 16 + l15) * 64 + kh * 32 + l4 * 8);
#pragma unroll
      for (int mi = 0; mi < 2; ++mi)
#pragma unroll
        for (int ni = 0; ni < 4; ++ni)
          s[mi][ni] = __builtin_amdgcn_mfma_f32_16x16x32_bf16(
              qf[mi][kh], kf[ni], s[mi][ni], 0, 0, 0);
    }

    const bool needmask = (kv0 + 63 > q0);
#pragma unroll
    for (int mi = 0; mi < 2; ++mi) {
#pragma unroll
      for (int r = 0; r < 4; ++r) {
        float mx = -3e38f;
#pragma unroll
        for (int ni = 0; ni < 4; ++ni) {
          float sv = s[mi][ni][r] * 0.125f;
          if (needmask) {
            int qg = q0 + mi * 16 + l4 * 4 + r;
            int kg = kv0 + ni * 16 + l15;
            if (kg > qg) sv = -3e38f;
          }
          s[mi][ni][r] = sv;
          mx = fmaxf(mx, sv);
        }
#pragma unroll
        for (int msk = 1; msk < 16; msk <<= 1)
          mx = fmaxf(mx, __shfl_xor(mx, msk));
        float mo = m_run[mi][r];
        float mn = fmaxf(mo, mx);
        float scale = __expf(mo - mn);
        float rsum = 0.f;
#pragma unroll
        for (int ni = 0; ni < 4; ++ni) {
          float p = __expf(s[mi][ni][r] - mn);
          s[mi][ni][r] = p;
          rsum += p;
        }
#pragma unroll
        for (int msk = 1; msk < 16; msk <<= 1)
          rsum += __shfl_xor(rsum, msk);
        m_run[mi][r] = mn;
        l_run[mi][r] = l_run[mi][r] * scale + rsum;
#pragma unroll
        for (int ni = 0; ni < 4; ++ni)
          o_acc[mi][ni][r] *= scale;
      }
#pragma unroll
      for (int ni = 0; ni < 4; ++ni)
#pragma unroll
        for (int r = 0; r < 4; ++r)
          Pl[(mi * 16 + l4 * 4 + r) * 72 + ni * 16 + l15] = f2b(s[mi][ni][r]);
    }

    // O += P V  (P from wave-private LDS; V^T frags straight from global)
#pragma unroll
    for (int kh = 0; kh < 2; ++kh) {
      bh8 pf[2], vf[4];
#pragma unroll
      for (int mi = 0; mi < 2; ++mi)
        pf[mi] = *(const bh8*)(Pl + (mi * 16 + l15) * 72 + kh * 32 + l4 * 8);
#pragma unroll
      for (int ni = 0; ni < 4; ++ni)
        vf[ni] = *(const bh8*)(Vb + (size_t)(ni * 16 + l15) * 1024 + kv0 + kh * 32 + l4 * 8);
#pragma unroll
      for (int mi = 0; mi < 2; ++mi)
#pragma unroll
        for (int ni = 0; ni < 4; ++ni)
          o_acc[mi][ni] = __builtin_amdgcn_mfma_f32_16x16x32_bf16(
              pf[mi], vf[ni], o_acc[mi][ni], 0, 0, 0);
    }
  }

  // ---- merge the two partials (flash merge), wave 0 finalizes ----
  __syncthreads();
  float* Ol = (float*)&Pls[0][0];       // 32x68 f32 = 8704 B, fits both bufs
  if (wv == 1) {
#pragma unroll
    for (int mi = 0; mi < 2; ++mi)
#pragma unroll
      for (int r = 0; r < 4; ++r) {
        int row = mi * 16 + l4 * 4 + r;
        if (l15 == 0) { MlLl[row] = m_run[mi][r]; MlLl[32 + row] = l_run[mi][r]; }
#pragma unroll
        for (int ni = 0; ni < 4; ++ni)
          Ol[row * 68 + ni * 16 + l15] = o_acc[mi][ni][r];
      }
  }
  __syncthreads();
  if (wv == 0) {
#pragma unroll
    for (int mi = 0; mi < 2; ++mi)
#pragma unroll
      for (int r = 0; r < 4; ++r) {
        int row = mi * 16 + l4 * 4 + r;
        float m1 = MlLl[row], l1 = MlLl[32 + row];
        float m0v = m_run[mi][r];
        float mn = fmaxf(m0v, m1);
        float s0 = __expf(m0v - mn), s1 = __expf(m1 - mn);
        float inv = 1.0f / (l_run[mi][r] * s0 + l1 * s1);
        int q = q0 + row;
#pragma unroll
        for (int ni = 0; ni < 4; ++ni) {
          int d = ni * 16 + l15;
          float o = o_acc[mi][ni][r] * s0 + Ol[row * 68 + ni * 16 + l15] * s1;
          x[(size_t)(b * 1024 + q) * 768 + h * 64 + d] += o * inv;
        }
      }
  }
}

// ---------------------------------------------------------------------------
// Merge per-block loss partials: lrow[row] = (logsumexp - logit[target])/4096
__global__ __launch_bounds__(256) void lossmerge_kernel(
    const float* __restrict__ pm, const float* __restrict__ ps,
    const float* __restrict__ logits, const int* __restrict__ targets,
    float* __restrict__ lrow)
{
  __shared__ float red[256];
  int row = blockIdx.x, tid = threadIdx.x;
  const float* pmr = pm + (size_t)row * 500;
  const float* psr = ps + (size_t)row * 500;
  float m = -3e38f;
  for (int i = tid; i < 500; i += 256) m = fmaxf(m, pmr[i]);
  red[tid] = m; __syncthreads();
  for (int o = 128; o > 0; o >>= 1) { if (tid < o) red[tid] = fmaxf(red[tid], red[tid + o]); __syncthreads(); }
  m = red[0]; __syncthreads();
  float s = 0.f;
  for (int i = tid; i < 500; i += 256) s += psr[i] * __expf(pmr[i] - m);
  red[tid] = s; __syncthreads();
  for (int o = 128; o > 0; o >>= 1) { if (tid < o) red[tid] += red[tid + o]; __syncthreads(); }
  if (tid == 0) {
    float lse = m + logf(red[0]);
    lrow[row] = (lse - logits[(size_t)row * 32000 + targets[row]]) * (1.0f / 4096.0f);
  }
}

// Standalone per-row cross-entropy (fallback when ws too small for partials).
__global__ __launch_bounds__(256) void lossrow_kernel(
    const float* __restrict__ logits, const int* __restrict__ targets,
    float* __restrict__ lrow)
{
  __shared__ float red[256];
  int row = blockIdx.x, tid = threadIdx.x;
  const float* lr = logits + (size_t)row * 32000;
  const float4* lr4 = (const float4*)lr;
  float lmax = -1e30f;
  for (int i = tid; i < 8000; i += 256) {
    float4 v = lr4[i];
    lmax = fmaxf(fmaxf(lmax, fmaxf(v.x, v.y)), fmaxf(v.z, v.w));
  }
  red[tid] = lmax; __syncthreads();
  for (int o = 128; o > 0; o >>= 1) { if (tid < o) red[tid] = fmaxf(red[tid], red[tid + o]); __syncthreads(); }
  float m = red[0]; __syncthreads();
  float ls = 0.f;
  for (int i = tid; i < 8000; i += 256) {
    float4 v = lr4[i];
    ls += expf(v.x - m) + expf(v.y - m) + expf(v.z - m) + expf(v.w - m);
  }
  red[tid] = ls; __syncthreads();
  for (int o = 128; o > 0; o >>= 1) { if (tid < o) red[tid] += red[tid + o]; __syncthreads(); }
  if (tid == 0) {
    float lse = m + logf(red[0]);
    lrow[row] = (lse - lr[targets[row]]) * (1.0f / 4096.0f);
  }
}

__global__ __launch_bounds__(256) void lossred_kernel(
    const float* __restrict__ lrow, float* __restrict__ out)
{
  __shared__ float red[256];
  int tid = threadIdx.x;
  float s = 0.f;
  for (int i = tid; i < 4096; i += 256) s += lrow[i];
  red[tid] = s; __syncthreads();
  for (int o = 128; o > 0; o >>= 1) { if (tid < o) red[tid] += red[tid + o]; __syncthreads(); }
  if (tid == 0) out[0] = red[0];
}

// ---------------------------------------------------------------------------
extern "C" void kernel_launch(void* const* d_in, const int* in_sizes, int n_in,
                              void* d_out, int out_size, void* d_ws, size_t ws_size,
                              hipStream_t stream)
{
  (void)in_sizes; (void)n_in; (void)out_size;
  const int Bq = 4, T = 1024, V = 32000, C = 768, L = 6;
  const int M = Bq * T;   // 4096

  const int*   idx     = (const int*)d_in[0];
  const int*   targets = (const int*)d_in[1];
  const float* tok     = (const float*)d_in[2];
  const float* pos     = (const float*)d_in[3];
  const float* Wq      = (const float*)d_in[4];
  const float* Wk      = (const float*)d_in[5];
  const float* Wv      = (const float*)d_in[6];
  const float* ln1s    = (const float*)d_in[7];
  const float* ln1b    = (const float*)d_in[8];
  const float* ln2s    = (const float*)d_in[9];
  const float* ln2b    = (const float*)d_in[10];
  const float* W1      = (const float*)d_in[11];
  const float* b1      = (const float*)d_in[12];
  const float* W2      = (const float*)d_in[13];
  const float* b2      = (const float*)d_in[14];
  const float* lnfs    = (const float*)d_in[15];
  const float* lnfb    = (const float*)d_in[16];
  const float* Wout    = (const float*)d_in[17];
  const float* bout    = (const float*)d_in[18];
  float* out = (float*)d_out;

  // ---- scratch inside d_out's logits region (dead until logits GEMM) ----
  char* ob = (char*)d_out;
  size_t oo = 0;
  auto oa = [&](size_t bytes) {
    void* p = ob + oo; oo += (bytes + 255) & ~(size_t)255; return p;
  };
  float*          x     = (float*)oa((size_t)M * C * 4);              // 12.6 MB
  unsigned short* qkvb  = (unsigned short*)oa((size_t)3 * 48 * 65536 * 2); // 18.9 MB
  unsigned short* hb    = (unsigned short*)oa((size_t)M * 3072 * 2);  // 25.2 MB
  unsigned short* Wqkvt = (unsigned short*)oa((size_t)L * 2304 * C * 2);
  unsigned short* W1t   = (unsigned short*)oa((size_t)L * C * 3072 * 2);
  unsigned short* W2t   = (unsigned short*)oa((size_t)L * C * 3072 * 2);
  // total ~135 MB << 524 MB logits region

  // ---- d_ws tiers ----
  char* wp = (char*)d_ws;
  unsigned short* xnb  = (unsigned short*)wp;                      // 6.29 MB
  float*          lrow = (float*)(wp + (size_t)M * C * 2);         // 16 KB
  float*          pm   = (float*)(wp + (size_t)M * C * 2 + 16384);
  float*          ps   = pm + (size_t)M * 500;                     // 2x 8.19 MB
  const size_t off_wbt_full  = (size_t)M * C * 2 + 16384 + (size_t)M * 500 * 8;
  const size_t off_wbt_small = (size_t)M * C * 2 + 16384;
  const size_t wbt_bytes = (size_t)V * C * 2;                      // 49.15 MB
  const bool full_ws = ws_size >= off_wbt_full + wbt_bytes;        // ~72 MB
  const bool wbt_ok  = full_ws || ws_size >= off_wbt_small + wbt_bytes;
  unsigned short* Wbt = (unsigned short*)(wp + (full_ws ? off_wbt_full
                                                        : off_wbt_small));

  // ---- pre-pass: embed + weight transpose/convert ----
  embed_kernel<<<(M * C) / 256, 256, 0, stream>>>(idx, tok, pos, x);
  tqkv_kernel<<<dim3(12, 72), 256, 0, stream>>>(Wq, Wqkvt, 0);
  tqkv_kernel<<<dim3(12, 72), 256, 0, stream>>>(Wk, Wqkvt, 1);
  tqkv_kernel<<<dim3(12, 72), 256, 0, stream>>>(Wv, Wqkvt, 2);
  tconv_kernel<<<dim3(48, 12, 6), 256, 0, stream>>>(W1, W1t, C, 3072);
  tconv_kernel<<<dim3(12, 48, 6), 256, 0, stream>>>(W2, W2t, 3072, C);
  if (wbt_ok)
    tconv_kernel<<<dim3(500, 12, 1), 256, 0, stream>>>(Wout, Wbt, C, V);

  for (int l = 0; l < L; ++l) {
    ln_bf16_kernel<<<M, 256, 0, stream>>>(x, ln1s + l * C, ln1b + l * C, xnb);
    gemm_bf16<0><<<dim3(18, 32), 256, 0, stream>>>(
        xnb, Wqkvt + (size_t)l * 2304 * C, nullptr, nullptr, qkvb, 2304, C);
    attn_mfma_kernel<<<dim3(32, 48), 128, 0, stream>>>(qkvb, x);
    ln_bf16_kernel<<<M, 256, 0, stream>>>(x, ln2s + l * C, ln2b + l * C, xnb);
    gemm_bf16<1><<<dim3(24, 32), 256, 0, stream>>>(
        xnb, W1t + (size_t)l * C * 3072, b1 + (size_t)l * 3072, nullptr, hb, 3072, C);
    gemm_bf16<2><<<dim3(6, 32), 256, 0, stream>>>(
        hb, W2t + (size_t)l * C * 3072, b2 + (size_t)l * C, x, nullptr, C, 3072);
  }

  ln_bf16_kernel<<<M, 256, 0, stream>>>(x, lnfs, lnfb, xnb);
  if (wbt_ok)
    gemm_logits_bt<<<dim3(8000, 1), 256, 0, stream>>>(
        xnb, Wbt, bout, out, full_ws ? pm : nullptr, full_ws ? ps : nullptr);
  else
    gemm_logits<<<dim3(500, 16), 256, 0, stream>>>(xnb, Wout, bout, out);

  if (full_ws && wbt_ok)
    lossmerge_kernel<<<M, 256, 0, stream>>>(pm, ps, out, targets, lrow);
  else
    lossrow_kernel<<<M, 256, 0, stream>>>(out, targets, lrow);
  lossred_kernel<<<1, 256, 0, stream>>>(lrow, out + (size_t)M * V);
}

// Round 12
// 1396.240 us; speedup vs baseline: 1.3910x; 1.0890x over previous
//
#include <hip/hip_runtime.h>
#include <hip/hip_bf16.h>

// ---------------------------------------------------------------------------
// GPT forward (B=4, T=1024, V=32000, C=768, L=6, H=12, HD=64).
// bf16 MFMA GEMMs (reg-staged, XOR-swizzled LDS — round-5 proven structure)
// + barrier-free flash attention (QBLK=32, 2-wave kv-split, V^T from global)
// + loss partials fused into the logits GEMM epilogue.
//
// R9:  2-D rectangle partition for logits (8m x 125n per XCD): FETCH 104 MB.
// R10/R11/R13/R15: K-loop / staging structure edits: 0/5, all reverted.
// R12: split-K mlp2 with ATOMICS: regressed (4-way same-address contention).
// R14: single-pass LN (one barrier): 1524 us. R16 confirm: 1520.5 us BEST.
// R17: mlp2 occupancy fix, atomic-free: split-K x2 into SEPARATE partial
//      buffers (grid (6,32,2) = 384 blocks vs 192; 64 CUs were idle), and
//      the P+Q+b2 combine is FUSED into the next LayerNorm (lnadd kernel,
//      which reads/writes x anyway). Same rolled K-loop; row stride ld=3072
//      decoupled from chunk K=1536.  Predicted total 1520 -> ~1450.
//
// Memory plan:
//   d_out logits region (524 MB) = scratch until the final GEMM:
//     x(f32), qkvb(bf16), hb(bf16), bf16 weights, PQ (2x 12.6 MB fp32).
//   d_ws tiers: xnb | lrow | pm,ps (loss partials) | Wbt   (~72 MB)
//               fallback: xnb | lrow | Wbt                 (~55.5 MB)
// ---------------------------------------------------------------------------

typedef __attribute__((ext_vector_type(8))) short          bh8;   // 8 bf16
typedef __attribute__((ext_vector_type(4))) unsigned short us4;
typedef __attribute__((ext_vector_type(4))) float          fl4;

__device__ inline unsigned short f2b(float f) {   // fp32 -> bf16 RNE
  unsigned u = __float_as_uint(f);
  return (unsigned short)((u + 0x7fffu + ((u >> 16) & 1u)) >> 16);
}

// ---------------------------------------------------------------------------
__global__ __launch_bounds__(256) void embed_kernel(
    const int* __restrict__ idx, const float* __restrict__ tok,
    const float* __restrict__ pos, float* __restrict__ x)
{
  int i = blockIdx.x * 256 + threadIdx.x;        // [0, 4096*768)
  int bt = i / 768, c = i - bt * 768;
  int t = bt & 1023;
  x[i] = tok[(size_t)idx[bt] * 768 + c] + pos[t * 768 + c];
}

// LayerNorm over rows of 768, fp32 in, bf16 out.  Single-pass (sum,sumsq)
// wave reduce — 6 shfl_xor + one 4-wide LDS combine; ONE barrier.
__global__ __launch_bounds__(256) void ln_bf16_kernel(
    const float* __restrict__ x, const float* __restrict__ s,
    const float* __restrict__ b, unsigned short* __restrict__ out)
{
  __shared__ float redS[4], redQ[4];
  int row = blockIdx.x, tid = threadIdx.x;
  const float* xr = x + (size_t)row * 768;
  float v0 = xr[tid], v1 = xr[tid + 256], v2 = xr[tid + 512];
  float sm = v0 + v1 + v2;
  float sq = v0 * v0 + v1 * v1 + v2 * v2;
#pragma unroll
  for (int m = 1; m < 64; m <<= 1) {
    sm += __shfl_xor(sm, m);
    sq += __shfl_xor(sq, m);
  }
  int wv = tid >> 6;
  if ((tid & 63) == 0) { redS[wv] = sm; redQ[wv] = sq; }
  __syncthreads();
  float ts = redS[0] + redS[1] + redS[2] + redS[3];
  float tq = redQ[0] + redQ[1] + redQ[2] + redQ[3];
  float mu = ts * (1.0f / 768.0f);
  float var = tq * (1.0f / 768.0f) - mu * mu;
  float inv = rsqrtf(var + 1e-5f);
  unsigned short* outr = out + (size_t)row * 768;
  outr[tid]       = f2b((v0 - mu) * inv * s[tid]       + b[tid]);
  outr[tid + 256] = f2b((v1 - mu) * inv * s[tid + 256] + b[tid + 256]);
  outr[tid + 512] = f2b((v2 - mu) * inv * s[tid + 512] + b[tid + 512]);
}

// R17: LN fused with the mlp2 partial combine: x += P + Q + badd, write x
// back, then LayerNorm(x) -> bf16 out.  Same single-pass reduce.
__global__ __launch_bounds__(256) void lnadd_bf16_kernel(
    float* __restrict__ x, const float* __restrict__ P,
    const float* __restrict__ Q, const float* __restrict__ badd,
    const float* __restrict__ s, const float* __restrict__ b,
    unsigned short* __restrict__ out)
{
  __shared__ float redS[4], redQ[4];
  int row = blockIdx.x, tid = threadIdx.x;
  float* xr = x + (size_t)row * 768;
  const float* Pr = P + (size_t)row * 768;
  const float* Qr = Q + (size_t)row * 768;
  float v0 = xr[tid]       + Pr[tid]       + Qr[tid]       + badd[tid];
  float v1 = xr[tid + 256] + Pr[tid + 256] + Qr[tid + 256] + badd[tid + 256];
  float v2 = xr[tid + 512] + Pr[tid + 512] + Qr[tid + 512] + badd[tid + 512];
  xr[tid] = v0; xr[tid + 256] = v1; xr[tid + 512] = v2;
  float sm = v0 + v1 + v2;
  float sq = v0 * v0 + v1 * v1 + v2 * v2;
#pragma unroll
  for (int m = 1; m < 64; m <<= 1) {
    sm += __shfl_xor(sm, m);
    sq += __shfl_xor(sq, m);
  }
  int wv = tid >> 6;
  if ((tid & 63) == 0) { redS[wv] = sm; redQ[wv] = sq; }
  __syncthreads();
  float ts = redS[0] + redS[1] + redS[2] + redS[3];
  float tq = redQ[0] + redQ[1] + redQ[2] + redQ[3];
  float mu = ts * (1.0f / 768.0f);
  float var = tq * (1.0f / 768.0f) - mu * mu;
  float inv = rsqrtf(var + 1e-5f);
  unsigned short* outr = out + (size_t)row * 768;
  outr[tid]       = f2b((v0 - mu) * inv * s[tid]       + b[tid]);
  outr[tid + 256] = f2b((v1 - mu) * inv * s[tid + 256] + b[tid + 256]);
  outr[tid + 512] = f2b((v2 - mu) * inv * s[tid + 512] + b[tid + 512]);
}

// ---------------------------------------------------------------------------
// Weight pre-transpose: fp32 [K][N] -> bf16 [N][K].  64x64 tiles.
__global__ __launch_bounds__(256) void tconv_kernel(
    const float* __restrict__ src, unsigned short* __restrict__ dst,
    int K, int N)
{
  __shared__ float tt[64][65];
  int n0 = blockIdx.x * 64, k0 = blockIdx.y * 64;
  const float* s = src + (size_t)blockIdx.z * K * N;
  unsigned short* d = dst + (size_t)blockIdx.z * K * N;
  int tx = threadIdx.x & 63, g = threadIdx.x >> 6;
#pragma unroll
  for (int i = 0; i < 16; ++i) {
    int k = g * 16 + i;
    tt[k][tx] = s[(size_t)(k0 + k) * N + n0 + tx];
  }
  __syncthreads();
#pragma unroll
  for (int i = 0; i < 16; ++i) {
    int n = g * 16 + i;
    d[(size_t)(n0 + n) * K + k0 + tx] = f2b(tt[tx][n]);
  }
}

// QKV weights: Wq[l][h][768][64] -> Wqkvt[l][which*768 + h*64 + d][768] bf16
__global__ __launch_bounds__(256) void tqkv_kernel(
    const float* __restrict__ src, unsigned short* __restrict__ dst, int which)
{
  __shared__ float tt[64][65];
  int k0 = blockIdx.x * 64;
  int z = blockIdx.y;                    // l*12 + h
  int l = z / 12, h = z - l * 12;
  const float* s = src + (size_t)z * 768 * 64;
  unsigned short* d = dst + (size_t)l * 2304 * 768 +
                      (size_t)(which * 768 + h * 64) * 768;
  int tx = threadIdx.x & 63, g = threadIdx.x >> 6;
#pragma unroll
  for (int i = 0; i < 16; ++i) {
    int k = g * 16 + i;
    tt[k][tx] = s[(size_t)(k0 + k) * 64 + tx];
  }
  __syncthreads();
#pragma unroll
  for (int i = 0; i < 16; ++i) {
    int n = g * 16 + i;
    d[(size_t)n * 768 + k0 + tx] = f2b(tt[tx][n]);
  }
}

// ---------------------------------------------------------------------------
// MFMA GEMM (round-5 structure): C = A @ Bt^T, 128x128 tile, BK=64, 4 waves,
// reg-staged XOR-swizzled LDS, register prefetch of tile t+1 before MFMA(t).
// ld = row stride of A and Bt in ELEMENTS (== K except MODE 3).
// MODE 0: qkv epilogue -> Q,K as [bh][t][64]; V TRANSPOSED as [bh][d][t].
// MODE 1: OutH = bf16(relu(acc + bias))   (mlp hidden, row-major)
// MODE 2: OutF += acc + bias              (residual accumulate, fp32)
// MODE 3: split-K partial: blockIdx.z picks K-chunk (ld=3072, K=1536) and
//         the partial buffer (OutF + z*M*N); plain fp32 store, no bias.
template<int MODE>
__global__ __launch_bounds__(256) void gemm_bf16(
    const unsigned short* __restrict__ A, const unsigned short* __restrict__ Bt,
    const float* __restrict__ bias, float* __restrict__ OutF,
    unsigned short* __restrict__ OutH, int N, int K, int ld)
{
  __shared__ __align__(16) char As[128 * 64 * 2];
  __shared__ __align__(16) char Bs[128 * 64 * 2];
  const int tid = threadIdx.x;
  const int lane = tid & 63;
  const int wr = (tid >> 7) & 1, wc = (tid >> 6) & 1;
  const int m0 = blockIdx.y * 128, n0 = blockIdx.x * 128;
  const size_t Kb = (size_t)ld * 2;

  if constexpr (MODE == 3) {
    const int kz = blockIdx.z;
    A    += (size_t)kz * 1536;            // K-chunk offset within a row
    Bt   += (size_t)kz * 1536;
    OutF += (size_t)kz * 4096 * 768;      // partial buffer select
  }

  fl4 acc[4][4] = {};
  const int o0 = tid * 16;
  const int rA = wr * 64 + (lane & 15);
  const int rB = wc * 64 + (lane & 15);
  const int kcol = (lane >> 4) << 4;
  const int sw = (lane & 7) << 4;

  auto ldAB = [&](int t, bh8* a, bh8* b) {
#pragma unroll
    for (int p = 0; p < 4; ++p) {
      int o = o0 + p * 4096;
      int row = o >> 7, col = o & 127;
      a[p] = *(const bh8*)((const char*)A + (size_t)(m0 + row) * Kb + (size_t)t * 128 + col);
      b[p] = *(const bh8*)((const char*)Bt + (size_t)(n0 + row) * Kb + (size_t)t * 128 + col);
    }
  };

  const int nK = K >> 6;
  bh8 ca[4], cb[4];
  ldAB(0, ca, cb);
  for (int t = 0; t < nK; ++t) {
    __syncthreads();                    // previous tile's LDS reads done
#pragma unroll
    for (int p = 0; p < 4; ++p) {
      int o = o0 + p * 4096;
      int row = o >> 7;
      int phys = o ^ ((row & 7) << 4);
      *(bh8*)(As + phys) = ca[p];
      *(bh8*)(Bs + phys) = cb[p];
    }
    __syncthreads();
    bh8 na[4], nb[4];
    const bool more = (t + 1 < nK);
    if (more) ldAB(t + 1, na, nb);      // issue early; consumed next iter
#pragma unroll
    for (int kh = 0; kh < 2; ++kh) {
      bh8 af[4], bf[4];
#pragma unroll
      for (int i = 0; i < 4; ++i) {
        af[i] = *(const bh8*)(As + (rA + i * 16) * 128 + ((kh * 64 + kcol) ^ sw));
        bf[i] = *(const bh8*)(Bs + (rB + i * 16) * 128 + ((kh * 64 + kcol) ^ sw));
      }
#pragma unroll
      for (int mi = 0; mi < 4; ++mi)
#pragma unroll
        for (int ni = 0; ni < 4; ++ni)
          acc[mi][ni] = __builtin_amdgcn_mfma_f32_16x16x32_bf16(
              af[mi], bf[ni], acc[mi][ni], 0, 0, 0);
    }
    if (more) {
#pragma unroll
      for (int p = 0; p < 4; ++p) { ca[p] = na[p]; cb[p] = nb[p]; }
    }
  }

  const int er = (lane >> 4) << 2;      // C/D: row=(lane>>4)*4+reg, col=lane&15
  const int ec = lane & 15;
#pragma unroll
  for (int mi = 0; mi < 4; ++mi)
#pragma unroll
    for (int ni = 0; ni < 4; ++ni)
#pragma unroll
      for (int r = 0; r < 4; ++r) {
        int m = m0 + wr * 64 + mi * 16 + er + r;
        int n = n0 + wc * 64 + ni * 16 + ec;
        float v = acc[mi][ni][r];
        if (MODE == 0) {
          int which = n / 768, rem = n - which * 768;
          int hh = rem >> 6, dd = rem & 63;
          int bb = m >> 10, tt = m & 1023;
          size_t base = (size_t)(which * 48 + bb * 12 + hh) << 16;
          if (which == 2)               // V stored transposed [d][t]
            OutH[base + (size_t)dd * 1024 + tt] = f2b(v);
          else
            OutH[base + (tt << 6) + dd] = f2b(v);
        } else if (MODE == 1) {
          v += bias[n]; v = fmaxf(v, 0.0f);
          OutH[(size_t)m * N + n] = f2b(v);
        } else if (MODE == 2) {
          v += bias[n];
          OutF[(size_t)m * N + n] += v;
        } else {                        // MODE 3: plain partial store
          OutF[(size_t)m * N + n] = v;
        }
      }
}

// ---------------------------------------------------------------------------
// Logits GEMM + fused loss partials (R9/R12, harness-measured 301-312 us):
// Out[4096,32000] = xnb @ Wbt^T + bout.  Grid (8000,1).
// Tile grid 32m x 250n; each XCD (bid&7) owns an 8m x 125n rectangle,
// m-fastest inside -> per-XCD L2 working set (A-quarter 1.57 MB + ~10 B
// panels) < 4 MB L2; reads don't depend on L3 (which the 578 MB write
// stream thrashes).  Reg-staged XOR-swizzled LDS with t+1 reg prefetch.
// Out stores NON-TEMPORAL.  Partials indexed n_t*2+wc (500 groups).
__global__ __launch_bounds__(256) void gemm_logits_bt(
    const unsigned short* __restrict__ A, const unsigned short* __restrict__ Bt,
    const float* __restrict__ bias, float* __restrict__ Out,
    float* __restrict__ pm, float* __restrict__ ps)
{
  __shared__ __align__(16) char As[128 * 64 * 2];
  __shared__ __align__(16) char Bs[128 * 64 * 2];
  const int tid = threadIdx.x;
  const int lane = tid & 63;
  const int wr = (tid >> 7) & 1, wc = (tid >> 6) & 1;
  const int bid = blockIdx.x;
  const int xcd = bid & 7, lb = bid >> 3;           // lb in [0,1000)
  const int m_t = (xcd >> 1) * 8 + (lb & 7);        // 8 m-tiles per XCD
  const int n_t = (xcd & 1) * 125 + (lb >> 3);      // 125 n-tiles per XCD
  const int m0 = m_t * 128, n0 = n_t * 128;
  const size_t Kb = 1536;               // K=768 bf16

  fl4 acc[4][4] = {};
  const int o0 = tid * 16;
  const int rA = wr * 64 + (lane & 15);
  const int rB = wc * 64 + (lane & 15);
  const int kcol = (lane >> 4) << 4;
  const int sw = (lane & 7) << 4;

  auto ldAB = [&](int t, bh8* a, bh8* b) {
#pragma unroll
    for (int p = 0; p < 4; ++p) {
      int o = o0 + p * 4096;
      int row = o >> 7, col = o & 127;
      a[p] = *(const bh8*)((const char*)A + (size_t)(m0 + row) * Kb + (size_t)t * 128 + col);
      b[p] = *(const bh8*)((const char*)Bt + (size_t)(n0 + row) * Kb + (size_t)t * 128 + col);
    }
  };

  const int nK = 12;                    // 768 / 64
  bh8 ca[4], cb[4];
  ldAB(0, ca, cb);
  for (int t = 0; t < nK; ++t) {
    __syncthreads();                    // previous tile's LDS reads done
#pragma unroll
    for (int p = 0; p < 4; ++p) {
      int o = o0 + p * 4096;
      int row = o >> 7;
      int phys = o ^ ((row & 7) << 4);
      *(bh8*)(As + phys) = ca[p];
      *(bh8*)(Bs + phys) = cb[p];
    }
    __syncthreads();
    bh8 na[4], nb[4];
    const bool more = (t + 1 < nK);
    if (more) ldAB(t + 1, na, nb);      // issue early; consumed next iter
#pragma unroll
    for (int kh = 0; kh < 2; ++kh) {
      bh8 af[4], bf[4];
#pragma unroll
      for (int i = 0; i < 4; ++i) {
        af[i] = *(const bh8*)(As + (rA + i * 16) * 128 + ((kh * 64 + kcol) ^ sw));
        bf[i] = *(const bh8*)(Bs + (rB + i * 16) * 128 + ((kh * 64 + kcol) ^ sw));
      }
#pragma unroll
      for (int mi = 0; mi < 4; ++mi)
#pragma unroll
        for (int ni = 0; ni < 4; ++ni)
          acc[mi][ni] = __builtin_amdgcn_mfma_f32_16x16x32_bf16(
              af[mi], bf[ni], acc[mi][ni], 0, 0, 0);
    }
    if (more) {
#pragma unroll
      for (int p = 0; p < 4; ++p) { ca[p] = na[p]; cb[p] = nb[p]; }
    }
  }

  const int er = (lane >> 4) << 2;
  const int ec = lane & 15;
#pragma unroll
  for (int mi = 0; mi < 4; ++mi)
#pragma unroll
    for (int r = 0; r < 4; ++r) {
      int m = m0 + wr * 64 + mi * 16 + er + r;
      float tv[4];
#pragma unroll
      for (int ni = 0; ni < 4; ++ni) {
        int n = n0 + wc * 64 + ni * 16 + ec;
        tv[ni] = acc[mi][ni][r] + bias[n];
        __builtin_nontemporal_store(tv[ni], &Out[(size_t)m * 32000 + n]);
      }
      if (pm) {
        float mx = fmaxf(fmaxf(tv[0], tv[1]), fmaxf(tv[2], tv[3]));
#pragma unroll
        for (int msk = 1; msk < 16; msk <<= 1)
          mx = fmaxf(mx, __shfl_xor(mx, msk));
        float ss = __expf(tv[0] - mx) + __expf(tv[1] - mx) +
                   __expf(tv[2] - mx) + __expf(tv[3] - mx);
#pragma unroll
        for (int msk = 1; msk < 16; msk <<= 1)
          ss += __shfl_xor(ss, msk);
        if (ec == 0) {
          pm[(size_t)m * 500 + n_t * 2 + wc] = mx;
          ps[(size_t)m * 500 + n_t * 2 + wc] = ss;
        }
      }
    }
}

// ---------------------------------------------------------------------------
// Fallback logits GEMM (in-kernel W fp32->bf16 staging).
__global__ __launch_bounds__(256) void gemm_logits(
    const unsigned short* __restrict__ A, const float* __restrict__ W,
    const float* __restrict__ bias, float* __restrict__ Out)
{
  __shared__ __align__(16) char As[256 * 64 * 2];   // 32 KB
  __shared__ __align__(16) char Bs[64 * 64 * 2];    // 8 KB
  const int tid = threadIdx.x, lane = tid & 63, wid = tid >> 6;
  const int m0 = blockIdx.y * 256, n0 = blockIdx.x * 64;
  const size_t Kb = 1536;

  fl4 acc[4][4] = {};
  const int o0 = tid * 16;
  const int rA = wid * 64 + (lane & 15);
  const int rB = (lane & 15);
  const int kcol = (lane >> 4) << 4;
  const int sw = (lane & 7) << 4;
  const int bn = tid & 63, bg = tid >> 6;

  for (int t = 0; t < 12; ++t) {
    bh8 ra[8];
#pragma unroll
    for (int p = 0; p < 8; ++p) {
      int o = o0 + p * 4096;
      int row = o >> 7, col = o & 127;
      ra[p] = *(const bh8*)((const char*)A + (size_t)(m0 + row) * Kb + (size_t)t * 128 + col);
    }
    unsigned short rb[16];
#pragma unroll
    for (int p = 0; p < 4; ++p) {
      int q = p * 4 + bg;               // k-quad 0..15
#pragma unroll
      for (int i = 0; i < 4; ++i)
        rb[p * 4 + i] = f2b(W[(size_t)(t * 64 + q * 4 + i) * 32000 + n0 + bn]);
    }
    __syncthreads();
#pragma unroll
    for (int p = 0; p < 8; ++p) {
      int o = o0 + p * 4096;
      int row = o >> 7;
      *(bh8*)(As + (o ^ ((row & 7) << 4))) = ra[p];
    }
#pragma unroll
    for (int p = 0; p < 4; ++p) {
      int q = p * 4 + bg;
      int o = bn * 128 + q * 8;
      us4 w4 = { rb[p * 4], rb[p * 4 + 1], rb[p * 4 + 2], rb[p * 4 + 3] };
      *(us4*)(Bs + (o ^ ((bn & 7) << 4))) = w4;
    }
    __syncthreads();
#pragma unroll
    for (int kh = 0; kh < 2; ++kh) {
      bh8 af[4], bf[4];
#pragma unroll
      for (int i = 0; i < 4; ++i) {
        af[i] = *(const bh8*)(As + (rA + i * 16) * 128 + ((kh * 64 + kcol) ^ sw));
        bf[i] = *(const bh8*)(Bs + (rB + i * 16) * 128 + ((kh * 64 + kcol) ^ sw));
      }
#pragma unroll
      for (int mi = 0; mi < 4; ++mi)
#pragma unroll
        for (int ni = 0; ni < 4; ++ni)
          acc[mi][ni] = __builtin_amdgcn_mfma_f32_16x16x32_bf16(
              af[mi], bf[ni], acc[mi][ni], 0, 0, 0);
    }
    __syncthreads();
  }

  const int er = (lane >> 4) << 2, ec = lane & 15;
#pragma unroll
  for (int mi = 0; mi < 4; ++mi)
#pragma unroll
    for (int ni = 0; ni < 4; ++ni)
#pragma unroll
      for (int r = 0; r < 4; ++r) {
        int m = m0 + wid * 64 + mi * 16 + er + r;
        int n = n0 + ni * 16 + ec;
        __builtin_nontemporal_store(acc[mi][ni][r] + bias[n],
                                    &Out[(size_t)m * 32000 + n]);
      }
}

// ---------------------------------------------------------------------------
// Flash attention, bf16 MFMA.  QBLK=32, 2 waves/block, kv-split by wave.
// Q,K layout [bh][t][64]; V layout [bh][d][t] (transposed by QKV epilogue) so
// PV B-fragments read directly from global — no V staging, and the kv loop is
// BARRIER-FREE (each wave's P-buffer is wave-private; lgkmcnt orders it).
__global__ __launch_bounds__(128) void attn_mfma_kernel(
    const unsigned short* __restrict__ qkvb, float* __restrict__ x)
{
  __shared__ __align__(16) unsigned short Pls[2][32 * 72];  // per-wave P
  __shared__ float MlLl[64];
  const int tid = threadIdx.x;
  const int lane = tid & 63, wv = tid >> 6;
  const int bh = blockIdx.y;
  const int b = bh / 12, h = bh - b * 12;
  const int qt = blockIdx.x, q0 = qt * 32;
  const int l15 = lane & 15, l4 = lane >> 4;
  const unsigned short* Qb = qkvb + ((size_t)bh << 16);
  const unsigned short* Kb = qkvb + ((size_t)(48 + bh) << 16);
  const unsigned short* Vb = qkvb + ((size_t)(96 + bh) << 16);  // [d][t]
  unsigned short* Pl = Pls[wv];

  bh8 qf[2][2];
#pragma unroll
  for (int mi = 0; mi < 2; ++mi)
#pragma unroll
    for (int kh = 0; kh < 2; ++kh)
      qf[mi][kh] = *(const bh8*)(Qb + (size_t)(q0 + mi * 16 + l15) * 64 + kh * 32 + l4 * 8);

  fl4 o_acc[2][4] = {};
  fl4 m_run[2], l_run[2];
#pragma unroll
  for (int mi = 0; mi < 2; ++mi) {
    m_run[mi] = fl4{-3e38f, -3e38f, -3e38f, -3e38f};
    l_run[mi] = fl4{0.f, 0.f, 0.f, 0.f};
  }

  const int nkv = (qt >> 1) + 1;        // # of 64-wide kv tiles needed
  for (int j = wv; j < nkv; j += 2) {   // barrier-free: waves independent
    const int kv0 = j * 64;
    fl4 s[2][4] = {};
#pragma unroll
    for (int kh = 0; kh < 2; ++kh) {
      bh8 kf[4];
#pragma unroll
      for (int ni = 0; ni < 4; ++ni)
        kf[ni] = *(const bh8*)(Kb + (size_t)(kv0 + ni * 16 + l15) * 64 + kh * 32 + l4 * 8);
#pragma unroll
      for (int mi = 0; mi < 2; ++mi)
#pragma unroll
        for (int ni = 0; ni < 4; ++ni)
          s[mi][ni] = __builtin_amdgcn_mfma_f32_16x16x32_bf16(
              qf[mi][kh], kf[ni], s[mi][ni], 0, 0, 0);
    }

    const bool needmask = (kv0 + 63 > q0);
#pragma unroll
    for (int mi = 0; mi < 2; ++mi) {
#pragma unroll
      for (int r = 0; r < 4; ++r) {
        float mx = -3e38f;
#pragma unroll
        for (int ni = 0; ni < 4; ++ni) {
          float sv = s[mi][ni][r] * 0.125f;
          if (needmask) {
            int qg = q0 + mi * 16 + l4 * 4 + r;
            int kg = kv0 + ni * 16 + l15;
            if (kg > qg) sv = -3e38f;
          }
          s[mi][ni][r] = sv;
          mx = fmaxf(mx, sv);
        }
#pragma unroll
        for (int msk = 1; msk < 16; msk <<= 1)
          mx = fmaxf(mx, __shfl_xor(mx, msk));
        float mo = m_run[mi][r];
        float mn = fmaxf(mo, mx);
        float scale = __expf(mo - mn);
        float rsum = 0.f;
#pragma unroll
        for (int ni = 0; ni < 4; ++ni) {
          float p = __expf(s[mi][ni][r] - mn);
          s[mi][ni][r] = p;
          rsum += p;
        }
#pragma unroll
        for (int msk = 1; msk < 16; msk <<= 1)
          rsum += __shfl_xor(rsum, msk);
        m_run[mi][r] = mn;
        l_run[mi][r] = l_run[mi][r] * scale + rsum;
#pragma unroll
        for (int ni = 0; ni < 4; ++ni)
          o_acc[mi][ni][r] *= scale;
      }
#pragma unroll
      for (int ni = 0; ni < 4; ++ni)
#pragma unroll
        for (int r = 0; r < 4; ++r)
          Pl[(mi * 16 + l4 * 4 + r) * 72 + ni * 16 + l15] = f2b(s[mi][ni][r]);
    }

    // O += P V  (P from wave-private LDS; V^T frags straight from global)
#pragma unroll
    for (int kh = 0; kh < 2; ++kh) {
      bh8 pf[2], vf[4];
#pragma unroll
      for (int mi = 0; mi < 2; ++mi)
        pf[mi] = *(const bh8*)(Pl + (mi * 16 + l15) * 72 + kh * 32 + l4 * 8);
#pragma unroll
      for (int ni = 0; ni < 4; ++ni)
        vf[ni] = *(const bh8*)(Vb + (size_t)(ni * 16 + l15) * 1024 + kv0 + kh * 32 + l4 * 8);
#pragma unroll
      for (int mi = 0; mi < 2; ++mi)
#pragma unroll
        for (int ni = 0; ni < 4; ++ni)
          o_acc[mi][ni] = __builtin_amdgcn_mfma_f32_16x16x32_bf16(
              pf[mi], vf[ni], o_acc[mi][ni], 0, 0, 0);
    }
  }

  // ---- merge the two partials (flash merge), wave 0 finalizes ----
  __syncthreads();
  float* Ol = (float*)&Pls[0][0];       // 32x68 f32 = 8704 B, fits both bufs
  if (wv == 1) {
#pragma unroll
    for (int mi = 0; mi < 2; ++mi)
#pragma unroll
      for (int r = 0; r < 4; ++r) {
        int row = mi * 16 + l4 * 4 + r;
        if (l15 == 0) { MlLl[row] = m_run[mi][r]; MlLl[32 + row] = l_run[mi][r]; }
#pragma unroll
        for (int ni = 0; ni < 4; ++ni)
          Ol[row * 68 + ni * 16 + l15] = o_acc[mi][ni][r];
      }
  }
  __syncthreads();
  if (wv == 0) {
#pragma unroll
    for (int mi = 0; mi < 2; ++mi)
#pragma unroll
      for (int r = 0; r < 4; ++r) {
        int row = mi * 16 + l4 * 4 + r;
        float m1 = MlLl[row], l1 = MlLl[32 + row];
        float m0v = m_run[mi][r];
        float mn = fmaxf(m0v, m1);
        float s0 = __expf(m0v - mn), s1 = __expf(m1 - mn);
        float inv = 1.0f / (l_run[mi][r] * s0 + l1 * s1);
        int q = q0 + row;
#pragma unroll
        for (int ni = 0; ni < 4; ++ni) {
          int d = ni * 16 + l15;
          float o = o_acc[mi][ni][r] * s0 + Ol[row * 68 + ni * 16 + l15] * s1;
          x[(size_t)(b * 1024 + q) * 768 + h * 64 + d] += o * inv;
        }
      }
  }
}

// ---------------------------------------------------------------------------
// Merge per-block loss partials: lrow[row] = (logsumexp - logit[target])/4096
__global__ __launch_bounds__(256) void lossmerge_kernel(
    const float* __restrict__ pm, const float* __restrict__ ps,
    const float* __restrict__ logits, const int* __restrict__ targets,
    float* __restrict__ lrow)
{
  __shared__ float red[256];
  int row = blockIdx.x, tid = threadIdx.x;
  const float* pmr = pm + (size_t)row * 500;
  const float* psr = ps + (size_t)row * 500;
  float m = -3e38f;
  for (int i = tid; i < 500; i += 256) m = fmaxf(m, pmr[i]);
  red[tid] = m; __syncthreads();
  for (int o = 128; o > 0; o >>= 1) { if (tid < o) red[tid] = fmaxf(red[tid], red[tid + o]); __syncthreads(); }
  m = red[0]; __syncthreads();
  float s = 0.f;
  for (int i = tid; i < 500; i += 256) s += psr[i] * __expf(pmr[i] - m);
  red[tid] = s; __syncthreads();
  for (int o = 128; o > 0; o >>= 1) { if (tid < o) red[tid] += red[tid + o]; __syncthreads(); }
  if (tid == 0) {
    float lse = m + logf(red[0]);
    lrow[row] = (lse - logits[(size_t)row * 32000 + targets[row]]) * (1.0f / 4096.0f);
  }
}

// Standalone per-row cross-entropy (fallback when ws too small for partials).
__global__ __launch_bounds__(256) void lossrow_kernel(
    const float* __restrict__ logits, const int* __restrict__ targets,
    float* __restrict__ lrow)
{
  __shared__ float red[256];
  int row = blockIdx.x, tid = threadIdx.x;
  const float* lr = logits + (size_t)row * 32000;
  const float4* lr4 = (const float4*)lr;
  float lmax = -1e30f;
  for (int i = tid; i < 8000; i += 256) {
    float4 v = lr4[i];
    lmax = fmaxf(fmaxf(lmax, fmaxf(v.x, v.y)), fmaxf(v.z, v.w));
  }
  red[tid] = lmax; __syncthreads();
  for (int o = 128; o > 0; o >>= 1) { if (tid < o) red[tid] = fmaxf(red[tid], red[tid + o]); __syncthreads(); }
  float m = red[0]; __syncthreads();
  float ls = 0.f;
  for (int i = tid; i < 8000; i += 256) {
    float4 v = lr4[i];
    ls += expf(v.x - m) + expf(v.y - m) + expf(v.z - m) + expf(v.w - m);
  }
  red[tid] = ls; __syncthreads();
  for (int o = 128; o > 0; o >>= 1) { if (tid < o) red[tid] += red[tid + o]; __syncthreads(); }
  if (tid == 0) {
    float lse = m + logf(red[0]);
    lrow[row] = (lse - lr[targets[row]]) * (1.0f / 4096.0f);
  }
}

__global__ __launch_bounds__(256) void lossred_kernel(
    const float* __restrict__ lrow, float* __restrict__ out)
{
  __shared__ float red[256];
  int tid = threadIdx.x;
  float s = 0.f;
  for (int i = tid; i < 4096; i += 256) s += lrow[i];
  red[tid] = s; __syncthreads();
  for (int o = 128; o > 0; o >>= 1) { if (tid < o) red[tid] += red[tid + o]; __syncthreads(); }
  if (tid == 0) out[0] = red[0];
}

// ---------------------------------------------------------------------------
extern "C" void kernel_launch(void* const* d_in, const int* in_sizes, int n_in,
                              void* d_out, int out_size, void* d_ws, size_t ws_size,
                              hipStream_t stream)
{
  (void)in_sizes; (void)n_in; (void)out_size;
  const int Bq = 4, T = 1024, V = 32000, C = 768, L = 6;
  const int M = Bq * T;   // 4096

  const int*   idx     = (const int*)d_in[0];
  const int*   targets = (const int*)d_in[1];
  const float* tok     = (const float*)d_in[2];
  const float* pos     = (const float*)d_in[3];
  const float* Wq      = (const float*)d_in[4];
  const float* Wk      = (const float*)d_in[5];
  const float* Wv      = (const float*)d_in[6];
  const float* ln1s    = (const float*)d_in[7];
  const float* ln1b    = (const float*)d_in[8];
  const float* ln2s    = (const float*)d_in[9];
  const float* ln2b    = (const float*)d_in[10];
  const float* W1      = (const float*)d_in[11];
  const float* b1      = (const float*)d_in[12];
  const float* W2      = (const float*)d_in[13];
  const float* b2      = (const float*)d_in[14];
  const float* lnfs    = (const float*)d_in[15];
  const float* lnfb    = (const float*)d_in[16];
  const float* Wout    = (const float*)d_in[17];
  const float* bout    = (const float*)d_in[18];
  float* out = (float*)d_out;

  // ---- scratch inside d_out's logits region (dead until logits GEMM) ----
  char* ob = (char*)d_out;
  size_t oo = 0;
  auto oa = [&](size_t bytes) {
    void* p = ob + oo; oo += (bytes + 255) & ~(size_t)255; return p;
  };
  float*          x     = (float*)oa((size_t)M * C * 4);              // 12.6 MB
  unsigned short* qkvb  = (unsigned short*)oa((size_t)3 * 48 * 65536 * 2); // 18.9 MB
  unsigned short* hb    = (unsigned short*)oa((size_t)M * 3072 * 2);  // 25.2 MB
  unsigned short* Wqkvt = (unsigned short*)oa((size_t)L * 2304 * C * 2);
  unsigned short* W1t   = (unsigned short*)oa((size_t)L * C * 3072 * 2);
  unsigned short* W2t   = (unsigned short*)oa((size_t)L * C * 3072 * 2);
  float*          PQ    = (float*)oa((size_t)2 * M * C * 4);          // 25.2 MB
  // total ~160 MB << 524 MB logits region

  // ---- d_ws tiers ----
  char* wp = (char*)d_ws;
  unsigned short* xnb  = (unsigned short*)wp;                      // 6.29 MB
  float*          lrow = (float*)(wp + (size_t)M * C * 2);         // 16 KB
  float*          pm   = (float*)(wp + (size_t)M * C * 2 + 16384);
  float*          ps   = pm + (size_t)M * 500;                     // 2x 8.19 MB
  const size_t off_wbt_full  = (size_t)M * C * 2 + 16384 + (size_t)M * 500 * 8;
  const size_t off_wbt_small = (size_t)M * C * 2 + 16384;
  const size_t wbt_bytes = (size_t)V * C * 2;                      // 49.15 MB
  const bool full_ws = ws_size >= off_wbt_full + wbt_bytes;        // ~72 MB
  const bool wbt_ok  = full_ws || ws_size >= off_wbt_small + wbt_bytes;
  unsigned short* Wbt = (unsigned short*)(wp + (full_ws ? off_wbt_full
                                                        : off_wbt_small));

  // ---- pre-pass: embed + weight transpose/convert ----
  embed_kernel<<<(M * C) / 256, 256, 0, stream>>>(idx, tok, pos, x);
  tqkv_kernel<<<dim3(12, 72), 256, 0, stream>>>(Wq, Wqkvt, 0);
  tqkv_kernel<<<dim3(12, 72), 256, 0, stream>>>(Wk, Wqkvt, 1);
  tqkv_kernel<<<dim3(12, 72), 256, 0, stream>>>(Wv, Wqkvt, 2);
  tconv_kernel<<<dim3(48, 12, 6), 256, 0, stream>>>(W1, W1t, C, 3072);
  tconv_kernel<<<dim3(12, 48, 6), 256, 0, stream>>>(W2, W2t, 3072, C);
  if (wbt_ok)
    tconv_kernel<<<dim3(500, 12, 1), 256, 0, stream>>>(Wout, Wbt, C, V);

  for (int l = 0; l < L; ++l) {
    if (l == 0)
      ln_bf16_kernel<<<M, 256, 0, stream>>>(x, ln1s, ln1b, xnb);
    else
      lnadd_bf16_kernel<<<M, 256, 0, stream>>>(
          x, PQ, PQ + (size_t)M * C, b2 + (size_t)(l - 1) * C,
          ln1s + l * C, ln1b + l * C, xnb);
    gemm_bf16<0><<<dim3(18, 32), 256, 0, stream>>>(
        xnb, Wqkvt + (size_t)l * 2304 * C, nullptr, nullptr, qkvb, 2304, C, C);
    attn_mfma_kernel<<<dim3(32, 48), 128, 0, stream>>>(qkvb, x);
    ln_bf16_kernel<<<M, 256, 0, stream>>>(x, ln2s + l * C, ln2b + l * C, xnb);
    gemm_bf16<1><<<dim3(24, 32), 256, 0, stream>>>(
        xnb, W1t + (size_t)l * C * 3072, b1 + (size_t)l * 3072, nullptr, hb,
        3072, C, C);
    gemm_bf16<3><<<dim3(6, 32, 2), 256, 0, stream>>>(
        hb, W2t + (size_t)l * C * 3072, nullptr, PQ, nullptr, C, 1536, 3072);
  }

  lnadd_bf16_kernel<<<M, 256, 0, stream>>>(
      x, PQ, PQ + (size_t)M * C, b2 + (size_t)(L - 1) * C, lnfs, lnfb, xnb);
  if (wbt_ok)
    gemm_logits_bt<<<dim3(8000, 1), 256, 0, stream>>>(
        xnb, Wbt, bout, out, full_ws ? pm : nullptr, full_ws ? ps : nullptr);
  else
    gemm_logits<<<dim3(500, 16), 256, 0, stream>>>(xnb, Wout, bout, out);

  if (full_ws && wbt_ok)
    lossmerge_kernel<<<M, 256, 0, stream>>>(pm, ps, out, targets, lrow);
  else
    lossrow_kernel<<<M, 256, 0, stream>>>(out, targets, lrow);
  lossred_kernel<<<1, 256, 0, stream>>>(lrow, out + (size_t)M * V);
}